// Round 1
// baseline (17949.048 us; speedup 1.0000x reference)
//
#include <hip/hip_runtime.h>
#include <hip/hip_bf16.h>

#define B_    4096
#define NC    32
#define DIM   64
#define INNER 128
#define HEADS 8
#define DH    16
#define DEPTH 6
#define FFH   512
#define FFI   256
#define NCONT 64
#define CATF  2048
#define KTOT  2112

typedef __attribute__((ext_vector_type(8))) short short8;
typedef __attribute__((ext_vector_type(4))) float f32x4;

__device__ __forceinline__ float bf2f(__hip_bfloat16 h) { return __bfloat162float(h); }

// ---------------------------------------------------------------------------
// Fused 6-layer transformer, one block per sample. x stays in LDS.
// ---------------------------------------------------------------------------
__global__ __launch_bounds__(256) void k_transformer(
    const int* __restrict__ x_categ, const float* __restrict__ embed,
    const float* __restrict__ ln1_g, const float* __restrict__ ln1_b,
    const float* __restrict__ wqkv,  const float* __restrict__ wo, const float* __restrict__ bo,
    const float* __restrict__ ln2_g, const float* __restrict__ ln2_b,
    const float* __restrict__ wff1,  const float* __restrict__ bff1,
    const float* __restrict__ wff2,  const float* __restrict__ bff2,
    __hip_bfloat16* __restrict__ Acat)
{
    __shared__ float xs[NC][65];          // residual stream
    __shared__ float qkv[NC][386];        // qkv (384) / reused as p (256)
    __shared__ float un[NC * 129];        // union: hs [32][65]  |  os [32][129]
#define hsv(r, c) un[(r) * 65 + (c)]
#define osv(r, c) un[(r) * 129 + (c)]

    const int b   = blockIdx.x;
    const int tid = threadIdx.x;

    // embedding gather
    for (int idx = tid; idx < NC * DIM; idx += 256) {
        int i = idx >> 6, j = idx & 63;
        int tok = x_categ[b * NC + i] + 2 + 100 * i;
        xs[i][j] = embed[tok * DIM + j];
    }
    __syncthreads();

    const int r = tid >> 3, s = tid & 7;   // 32 rows x 8 threads/row

    for (int d = 0; d < DEPTH; ++d) {
        const float* g1  = ln1_g + d * DIM;
        const float* b1  = ln1_b + d * DIM;
        const float* Wq  = wqkv  + d * DIM * 384;
        const float* Wo  = wo    + d * INNER * DIM;
        const float* Bo  = bo    + d * DIM;
        const float* g2  = ln2_g + d * DIM;
        const float* b2  = ln2_b + d * DIM;
        const float* W1  = wff1  + d * DIM * FFH;
        const float* Bf1 = bff1  + d * FFH;
        const float* W2  = wff2  + d * FFI * DIM;
        const float* Bf2 = bff2  + d * DIM;

        // ---- LN1: xs -> hs ----
        {
            float sum = 0.f, sq = 0.f;
            for (int j = s; j < 64; j += 8) { float v = xs[r][j]; sum += v; sq += v * v; }
            for (int m = 1; m < 8; m <<= 1) { sum += __shfl_xor(sum, m, 64); sq += __shfl_xor(sq, m, 64); }
            float mu = sum * (1.f / 64.f);
            float var = sq * (1.f / 64.f) - mu * mu;
            float ri = rsqrtf(var + 1e-5f);
            for (int j = s; j < 64; j += 8) hsv(r, j) = (xs[r][j] - mu) * ri * g1[j] + b1[j];
        }
        __syncthreads();

        // ---- qkv = hs @ Wq  ([32,64]@[64,384]) ----
        for (int part = 0; part < 3; ++part) {
            float acc[16];
#pragma unroll
            for (int j = 0; j < 16; ++j) acc[j] = 0.f;
            const float* Wp = Wq + part * 128 + s * 16;
            for (int k = 0; k < 64; ++k) {
                float hv = hsv(r, k);
                const float4* wrow = (const float4*)(Wp + k * 384);
#pragma unroll
                for (int q4 = 0; q4 < 4; ++q4) {
                    float4 wv = wrow[q4];
                    acc[q4 * 4 + 0] += hv * wv.x;
                    acc[q4 * 4 + 1] += hv * wv.y;
                    acc[q4 * 4 + 2] += hv * wv.z;
                    acc[q4 * 4 + 3] += hv * wv.w;
                }
            }
#pragma unroll
            for (int j = 0; j < 16; ++j) qkv[r][part * 128 + s * 16 + j] = acc[j];
        }
        __syncthreads();

        // ---- attention: thread = (head, query-row) ----
        {
            const int hh = tid >> 5, i = tid & 31;
            float qreg[16];
#pragma unroll
            for (int dd = 0; dd < 16; ++dd) qreg[dd] = qkv[i][hh * 16 + dd];
            float sim[32];
            float mx = -1e30f;
            for (int j = 0; j < 32; ++j) {
                float ss = 0.f;
#pragma unroll
                for (int dd = 0; dd < 16; ++dd) ss += qreg[dd] * qkv[j][128 + hh * 16 + dd];
                ss *= 0.25f;                       // DH^-0.5
                sim[j] = ss;
                mx = fmaxf(mx, ss);
            }
            float den = 0.f;
            for (int j = 0; j < 32; ++j) { float e = __expf(sim[j] - mx); sim[j] = e; den += e; }
            float rden = 1.f / den;
#pragma unroll
            for (int dd = 0; dd < 16; ++dd) {
                float od = 0.f;
                for (int j = 0; j < 32; ++j) od += sim[j] * qkv[j][256 + hh * 16 + dd];
                osv(i, hh * 16 + dd) = od * rden;
            }
        }
        __syncthreads();

        // ---- proj: xs += os @ Wo + Bo  ([32,128]@[128,64]) ----
        {
            float acc[8];
#pragma unroll
            for (int j = 0; j < 8; ++j) acc[j] = 0.f;
            for (int k = 0; k < 128; ++k) {
                float ov = osv(r, k);
                const float4* wrow = (const float4*)(Wo + k * 64 + s * 8);
                float4 w0 = wrow[0], w1 = wrow[1];
                acc[0] += ov * w0.x; acc[1] += ov * w0.y; acc[2] += ov * w0.z; acc[3] += ov * w0.w;
                acc[4] += ov * w1.x; acc[5] += ov * w1.y; acc[6] += ov * w1.z; acc[7] += ov * w1.w;
            }
#pragma unroll
            for (int j = 0; j < 8; ++j) { int c = s * 8 + j; xs[r][c] += acc[j] + Bo[c]; }
        }
        __syncthreads();

        // ---- LN2: xs -> hs ----
        {
            float sum = 0.f, sq = 0.f;
            for (int j = s; j < 64; j += 8) { float v = xs[r][j]; sum += v; sq += v * v; }
            for (int m = 1; m < 8; m <<= 1) { sum += __shfl_xor(sum, m, 64); sq += __shfl_xor(sq, m, 64); }
            float mu = sum * (1.f / 64.f);
            float var = sq * (1.f / 64.f) - mu * mu;
            float ri = rsqrtf(var + 1e-5f);
            for (int j = s; j < 64; j += 8) hsv(r, j) = (xs[r][j] - mu) * ri * g2[j] + b2[j];
        }
        __syncthreads();

        // ---- ff1 + geglu: p = (hs@W1[:, :256]+b) * gelu(hs@W1[:, 256:]+b) -> qkv[:, :256]
        for (int chunk = 0; chunk < 2; ++chunk) {
            float accA[16], accG[16];
#pragma unroll
            for (int j = 0; j < 16; ++j) { accA[j] = 0.f; accG[j] = 0.f; }
            const float* WA = W1 + s * 32 + chunk * 16;
            const float* WG = WA + 256;
            for (int k = 0; k < 64; ++k) {
                float hv = hsv(r, k);
                const float4* wa = (const float4*)(WA + k * 512);
                const float4* wg = (const float4*)(WG + k * 512);
#pragma unroll
                for (int q4 = 0; q4 < 4; ++q4) {
                    float4 va = wa[q4], vg = wg[q4];
                    accA[q4 * 4 + 0] += hv * va.x; accA[q4 * 4 + 1] += hv * va.y;
                    accA[q4 * 4 + 2] += hv * va.z; accA[q4 * 4 + 3] += hv * va.w;
                    accG[q4 * 4 + 0] += hv * vg.x; accG[q4 * 4 + 1] += hv * vg.y;
                    accG[q4 * 4 + 2] += hv * vg.z; accG[q4 * 4 + 3] += hv * vg.w;
                }
            }
#pragma unroll
            for (int j = 0; j < 16; ++j) {
                int c = s * 32 + chunk * 16 + j;
                float a = accA[j] + Bf1[c];
                float g = accG[j] + Bf1[256 + c];
                float gl = 0.5f * g * (1.f + erff(g * 0.70710678118654752f));  // exact gelu
                qkv[r][c] = a * gl;
            }
        }
        __syncthreads();

        // ---- ff2: xs += p @ W2 + Bf2  ([32,256]@[256,64]) ----
        {
            float acc[8];
#pragma unroll
            for (int j = 0; j < 8; ++j) acc[j] = 0.f;
            for (int k = 0; k < 256; ++k) {
                float pv = qkv[r][k];
                const float4* wrow = (const float4*)(W2 + k * 64 + s * 8);
                float4 w0 = wrow[0], w1 = wrow[1];
                acc[0] += pv * w0.x; acc[1] += pv * w0.y; acc[2] += pv * w0.z; acc[3] += pv * w0.w;
                acc[4] += pv * w1.x; acc[5] += pv * w1.y; acc[6] += pv * w1.z; acc[7] += pv * w1.w;
            }
#pragma unroll
            for (int j = 0; j < 8; ++j) { int c = s * 8 + j; xs[r][c] += acc[j] + Bf2[c]; }
        }
        __syncthreads();
    }

    // flat_categ -> bf16 (cols 0..2047 of Acat)
    for (int idx = tid; idx < NC * DIM; idx += 256)
        Acat[(size_t)b * KTOT + idx] = __float2bfloat16(xs[idx >> 6][idx & 63]);
#undef hsv
#undef osv
}

// ---------------------------------------------------------------------------
// BatchNorm1d (train-mode batch stats), one block per feature column.
// Writes fp32 normed and bf16 into Acat cols 2048..2111.
// ---------------------------------------------------------------------------
__global__ __launch_bounds__(256) void k_bn(
    const float* __restrict__ x_cont, const float* __restrict__ bn_g, const float* __restrict__ bn_b,
    float* __restrict__ normed, __hip_bfloat16* __restrict__ Acat)
{
    const int c = blockIdx.x;
    const int tid = threadIdx.x;
    float sum = 0.f, sq = 0.f;
    for (int rr = tid; rr < B_; rr += 256) { float v = x_cont[rr * NCONT + c]; sum += v; sq += v * v; }
    __shared__ float ssum[256], ssq[256];
    ssum[tid] = sum; ssq[tid] = sq;
    __syncthreads();
    for (int st = 128; st > 0; st >>= 1) {
        if (tid < st) { ssum[tid] += ssum[tid + st]; ssq[tid] += ssq[tid + st]; }
        __syncthreads();
    }
    float mu  = ssum[0] * (1.f / B_);
    float var = ssq[0] * (1.f / B_) - mu * mu;
    float ri  = rsqrtf(var + 1e-5f);
    float gg = bn_g[c], bb = bn_b[c];
    for (int rr = tid; rr < B_; rr += 256) {
        float v = (x_cont[rr * NCONT + c] - mu) * ri * gg + bb;
        normed[rr * NCONT + c] = v;
        Acat[(size_t)rr * KTOT + CATF + c] = __float2bfloat16(v);
    }
}

// ---------------------------------------------------------------------------
// g0_w [2112,2048] fp32  ->  WT [2048,2112] bf16 (transposed, k-contiguous)
// ---------------------------------------------------------------------------
__global__ __launch_bounds__(256) void k_transpose(
    const float* __restrict__ W, __hip_bfloat16* __restrict__ WT)
{
    __shared__ float tile[64][65];
    const int n0 = blockIdx.x * 64, k0 = blockIdx.y * 64;
    const int tid = threadIdx.x;
    for (int e = tid; e < 64 * 16; e += 256) {
        int rr = e >> 4, c4 = e & 15;
        float4 v = *(const float4*)&W[(size_t)(k0 + rr) * CATF + n0 + c4 * 4];
        tile[rr][c4 * 4 + 0] = v.x; tile[rr][c4 * 4 + 1] = v.y;
        tile[rr][c4 * 4 + 2] = v.z; tile[rr][c4 * 4 + 3] = v.w;
    }
    __syncthreads();
    for (int e = tid; e < 64 * 32; e += 256) {
        int n = e >> 5, kp = e & 31;
        __hip_bfloat16 h0 = __float2bfloat16(tile[kp * 2 + 0][n]);
        __hip_bfloat16 h1 = __float2bfloat16(tile[kp * 2 + 1][n]);
        unsigned u = ((unsigned)(*(unsigned short*)&h1) << 16) | (unsigned)(*(unsigned short*)&h0);
        *(unsigned*)&WT[(size_t)(n0 + n) * KTOT + k0 + kp * 2] = u;
    }
}

// ---------------------------------------------------------------------------
// G = relu(Acat[4096,2112] @ g0_w[2112,2048] + g0_b), bf16 MFMA, 128x128 tiles
// ---------------------------------------------------------------------------
__global__ __launch_bounds__(256) void k_gemm_g0(
    const __hip_bfloat16* __restrict__ Acat, const __hip_bfloat16* __restrict__ WT,
    const float* __restrict__ g0_b, __hip_bfloat16* __restrict__ G)
{
    __shared__ unsigned short At[128][40];   // padded to kill ds_read bank conflicts
    __shared__ unsigned short Bt[128][40];
    const int tid = threadIdx.x;
    const int m0 = blockIdx.y * 128, n0 = blockIdx.x * 128;
    const int w = tid >> 6, lane = tid & 63;
    const int wr = w >> 1, wc = w & 1;

    f32x4 acc[4][4];
#pragma unroll
    for (int mi = 0; mi < 4; ++mi)
#pragma unroll
        for (int ni = 0; ni < 4; ++ni) acc[mi][ni] = f32x4{0.f, 0.f, 0.f, 0.f};

    const int row_a = wr * 64 + (lane & 15);
    const int row_b = wc * 64 + (lane & 15);
    const int koff = (lane >> 4) * 8;

    for (int kt = 0; kt < KTOT / 32; ++kt) {
        const int k0 = kt * 32;
        for (int e = tid; e < 512; e += 256) {
            int rr = e >> 2, seg = e & 3;
            *(uint4*)&At[rr][seg * 8] = *(const uint4*)&Acat[(size_t)(m0 + rr) * KTOT + k0 + seg * 8];
        }
        for (int e = tid; e < 512; e += 256) {
            int rr = e >> 2, seg = e & 3;
            *(uint4*)&Bt[rr][seg * 8] = *(const uint4*)&WT[(size_t)(n0 + rr) * KTOT + k0 + seg * 8];
        }
        __syncthreads();
        short8 af[4], bfr[4];
#pragma unroll
        for (int mi = 0; mi < 4; ++mi) af[mi] = *(const short8*)&At[row_a + mi * 16][koff];
#pragma unroll
        for (int ni = 0; ni < 4; ++ni) bfr[ni] = *(const short8*)&Bt[row_b + ni * 16][koff];
#pragma unroll
        for (int mi = 0; mi < 4; ++mi)
#pragma unroll
            for (int ni = 0; ni < 4; ++ni)
                acc[mi][ni] = __builtin_amdgcn_mfma_f32_16x16x32_bf16(af[mi], bfr[ni], acc[mi][ni], 0, 0, 0);
        __syncthreads();
    }

#pragma unroll
    for (int mi = 0; mi < 4; ++mi)
#pragma unroll
        for (int ni = 0; ni < 4; ++ni)
#pragma unroll
            for (int reg = 0; reg < 4; ++reg) {
                int row = m0 + wr * 64 + mi * 16 + (lane >> 4) * 4 + reg;
                int col = n0 + wc * 64 + ni * 16 + (lane & 15);
                float v = acc[mi][ni][reg] + g0_b[col];
                G[(size_t)row * CATF + col] = __float2bfloat16(fmaxf(v, 0.f));
            }
}

// ---------------------------------------------------------------------------
// y1 = flat_categ @ y1_w + y1_b   (8 rows per block)
// ---------------------------------------------------------------------------
__global__ __launch_bounds__(256) void k_y1(
    const __hip_bfloat16* __restrict__ Acat, const float* __restrict__ y1_w,
    const float* __restrict__ y1_b, float* __restrict__ y1)
{
    const int b0 = blockIdx.x * 8;
    const int tid = threadIdx.x;
    const int c = tid & 63, q = tid >> 6;
    float acc[8];
#pragma unroll
    for (int rr = 0; rr < 8; ++rr) acc[rr] = 0.f;
    for (int k = q * 512; k < q * 512 + 512; ++k) {
        float wv = y1_w[k * 64 + c];
#pragma unroll
        for (int rr = 0; rr < 8; ++rr)
            acc[rr] += bf2f(Acat[(size_t)(b0 + rr) * KTOT + k]) * wv;
    }
    __shared__ float red[4][8][64];
#pragma unroll
    for (int rr = 0; rr < 8; ++rr) red[q][rr][c] = acc[rr];
    __syncthreads();
    for (int idx = tid; idx < 8 * 64; idx += 256) {
        int rr = idx >> 6, cc = idx & 63;
        float ssum = red[0][rr][cc] + red[1][rr][cc] + red[2][rr][cc] + red[3][rr][cc];
        y1[(b0 + rr) * 64 + cc] = ssum + y1_b[cc];
    }
}

// ---------------------------------------------------------------------------
// H = relu_gate * (normed @ h0_w):  yh on the fly, multiply by G. 4 rows/block
// ---------------------------------------------------------------------------
__global__ __launch_bounds__(256) void k_H(
    const float* __restrict__ normed, const float* __restrict__ h0_w,
    const __hip_bfloat16* __restrict__ G, __hip_bfloat16* __restrict__ H)
{
    const int b0 = blockIdx.x * 4;
    const int tid = threadIdx.x;
    __shared__ float nr[4][64];
    {
        int rr = tid >> 6, k = tid & 63;
        nr[rr][k] = normed[(b0 + rr) * NCONT + k];
    }
    __syncthreads();
    float acc[4][8];
#pragma unroll
    for (int rr = 0; rr < 4; ++rr)
#pragma unroll
        for (int j = 0; j < 8; ++j) acc[rr][j] = 0.f;
    for (int k = 0; k < 64; ++k) {
        float n0v = nr[0][k], n1v = nr[1][k], n2v = nr[2][k], n3v = nr[3][k];
#pragma unroll
        for (int j = 0; j < 8; ++j) {
            float wv = h0_w[k * CATF + tid + 256 * j];
            acc[0][j] += n0v * wv; acc[1][j] += n1v * wv;
            acc[2][j] += n2v * wv; acc[3][j] += n3v * wv;
        }
    }
#pragma unroll
    for (int rr = 0; rr < 4; ++rr)
#pragma unroll
        for (int j = 0; j < 8; ++j) {
            size_t off = (size_t)(b0 + rr) * CATF + tid + 256 * j;
            H[off] = __float2bfloat16(bf2f(G[off]) * acc[rr][j]);
        }
}

// ---------------------------------------------------------------------------
// Final: norms, alpha, c0/c1 combine, fc dot, sigmoid. One block per row.
// ---------------------------------------------------------------------------
__global__ __launch_bounds__(256) void k_final(
    const __hip_bfloat16* __restrict__ Acat, const __hip_bfloat16* __restrict__ H,
    const float* __restrict__ normed, const float* __restrict__ y1,
    const float* __restrict__ g1_w, const float* __restrict__ g1_b, const float* __restrict__ h1_w,
    const float* __restrict__ fc_w, const float* __restrict__ fc_b,
    float* __restrict__ out)
{
    const int b = blockIdx.x;
    const int tid = threadIdx.x;
    const __hip_bfloat16* xrow = Acat + (size_t)b * KTOT;
    const __hip_bfloat16* hrow = H + (size_t)b * CATF;

    __shared__ float r1[256], r2[256];
    float sx = 0.f, sh = 0.f;
    for (int n = tid; n < CATF; n += 256) {
        float xv = bf2f(xrow[n]); sx += xv * xv;
        float hv = bf2f(hrow[n]); sh += hv * hv;
    }
    r1[tid] = sx; r2[tid] = sh;
    __syncthreads();
    for (int st = 128; st > 0; st >>= 1) {
        if (tid < st) { r1[tid] += r1[tid + st]; r2[tid] += r2[tid + st]; }
        __syncthreads();
    }
    float alpha0 = fminf(fmaxf(sqrtf(r1[0]) / (sqrtf(r2[0]) + 1e-12f) * 0.2f, 0.f), 1.f);
    __syncthreads();

    float pd = 0.f;
    for (int n = tid; n < CATF; n += 256) {
        float c0 = bf2f(xrow[n]) + alpha0 * bf2f(hrow[n]);
        pd += c0 * fc_w[n];
    }
    r1[tid] = pd;
    __syncthreads();
    for (int st = 128; st > 0; st >>= 1) {
        if (tid < st) r1[tid] += r1[tid + st];
        __syncthreads();
    }
    float dot0 = r1[0];

    __shared__ float ny[128];
    __shared__ float c1dot;
    if (tid < 64) ny[tid] = normed[b * NCONT + tid];
    else if (tid < 128) ny[tid] = y1[b * NCONT + tid - 64];
    __syncthreads();

    if (tid < 64) {
        const int j = tid;
        float g = g1_b[j];
        for (int k = 0; k < 128; ++k) g += ny[k] * g1_w[k * 64 + j];
        g = fmaxf(g, 0.f);
        float hv = 0.f;
        for (int k = 0; k < 64; ++k) hv += ny[64 + k] * h1_w[k * 64 + j];
        float H1 = g * hv;
        float nj = ny[j];
        float snx = nj * nj, snh = H1 * H1;
        for (int m = 1; m < 64; m <<= 1) { snx += __shfl_xor(snx, m, 64); snh += __shfl_xor(snh, m, 64); }
        float a1 = fminf(fmaxf(sqrtf(snx) / (sqrtf(snh) + 1e-12f) * 0.2f, 0.f), 1.f);
        float d1 = (nj + a1 * H1) * fc_w[CATF + j];
        for (int m = 1; m < 64; m <<= 1) d1 += __shfl_xor(d1, m, 64);
        if (tid == 0) c1dot = d1;
    }
    __syncthreads();
    if (tid == 0) {
        float logit = dot0 + c1dot + fc_b[0];
        out[b] = 1.f / (1.f + expf(-logit));
    }
}

// ---------------------------------------------------------------------------
extern "C" void kernel_launch(void* const* d_in, const int* in_sizes, int n_in,
                              void* d_out, int out_size, void* d_ws, size_t ws_size,
                              hipStream_t stream)
{
    const int*   x_categ = (const int*)d_in[0];
    const float* x_cont  = (const float*)d_in[1];
    const float* embed   = (const float*)d_in[2];
    const float* ln1_g   = (const float*)d_in[3];
    const float* ln1_b   = (const float*)d_in[4];
    const float* wqkv    = (const float*)d_in[5];
    const float* wo      = (const float*)d_in[6];
    const float* bo      = (const float*)d_in[7];
    const float* ln2_g   = (const float*)d_in[8];
    const float* ln2_b   = (const float*)d_in[9];
    const float* wff1    = (const float*)d_in[10];
    const float* bff1    = (const float*)d_in[11];
    const float* wff2    = (const float*)d_in[12];
    const float* bff2    = (const float*)d_in[13];
    const float* bn_g    = (const float*)d_in[14];
    const float* bn_b    = (const float*)d_in[15];
    const float* g0_w    = (const float*)d_in[16];
    const float* g0_b    = (const float*)d_in[17];
    const float* h0_w    = (const float*)d_in[18];
    const float* y1_w    = (const float*)d_in[19];
    const float* y1_b    = (const float*)d_in[20];
    const float* g1_w    = (const float*)d_in[21];
    const float* g1_b    = (const float*)d_in[22];
    const float* h1_w    = (const float*)d_in[23];
    const float* fc_w    = (const float*)d_in[24];
    const float* fc_b    = (const float*)d_in[25];

    char* ws = (char*)d_ws;
    size_t off = 0;
    auto alloc = [&](size_t bytes) { void* p = ws + off; off += (bytes + 255) & ~255ULL; return p; };
    __hip_bfloat16* Acat = (__hip_bfloat16*)alloc((size_t)B_ * KTOT * 2);
    __hip_bfloat16* WT   = (__hip_bfloat16*)alloc((size_t)CATF * KTOT * 2);
    __hip_bfloat16* G    = (__hip_bfloat16*)alloc((size_t)B_ * CATF * 2);
    __hip_bfloat16* Hb   = (__hip_bfloat16*)alloc((size_t)B_ * CATF * 2);
    float* normed = (float*)alloc((size_t)B_ * NCONT * 4);
    float* y1     = (float*)alloc((size_t)B_ * NCONT * 4);

    k_transformer<<<B_, 256, 0, stream>>>(x_categ, embed, ln1_g, ln1_b, wqkv, wo, bo,
                                          ln2_g, ln2_b, wff1, bff1, wff2, bff2, Acat);
    k_bn<<<NCONT, 256, 0, stream>>>(x_cont, bn_g, bn_b, normed, Acat);
    k_transpose<<<dim3(CATF / 64, KTOT / 64), 256, 0, stream>>>(g0_w, WT);
    k_gemm_g0<<<dim3(CATF / 128, B_ / 128), 256, 0, stream>>>(Acat, WT, g0_b, G);
    k_y1<<<B_ / 8, 256, 0, stream>>>(Acat, y1_w, y1_b, y1);
    k_H<<<B_ / 4, 256, 0, stream>>>(normed, h0_w, G, Hb);
    k_final<<<B_, 256, 0, stream>>>(Acat, Hb, normed, y1, g1_w, g1_b, h1_w, fc_w, fc_b, (float*)d_out);
}

// Round 3
// 1474.714 us; speedup vs baseline: 12.1712x; 12.1712x over previous
//
#include <hip/hip_runtime.h>
#include <hip/hip_bf16.h>

#define B_    4096
#define NC    32
#define DIM   64
#define INNER 128
#define HEADS 8
#define DH    16
#define DEPTH 6
#define NCONT 64
#define CATF  2048
#define KTOT  2112
#define NROW  (B_ * NC)          // 131072 token rows

typedef __attribute__((ext_vector_type(8))) short short8;
typedef __attribute__((ext_vector_type(4))) float f32x4;

__device__ __forceinline__ float bf2f(__hip_bfloat16 h) { return __bfloat162float(h); }

// ---------------------------------------------------------------------------
// Generic weight transpose+cast: W [D][K][N] fp32 -> WT [D][N][K] bf16
// ---------------------------------------------------------------------------
__global__ __launch_bounds__(256) void k_wT(const float* __restrict__ W,
                                            __hip_bfloat16* __restrict__ WT,
                                            int K, int N)
{
    size_t idx = (size_t)blockIdx.x * 256 + threadIdx.x;
    int kn = K * N;
    int d = (int)(idx / kn), rem = (int)(idx % kn);
    int n = rem / K, k = rem % K;
    WT[idx] = __float2bfloat16(W[(size_t)d * kn + (size_t)k * N + n]);
}

// ---------------------------------------------------------------------------
// Embedding gather -> x fp32 [NROW, 64]
// ---------------------------------------------------------------------------
__global__ __launch_bounds__(256) void k_emb(const int* __restrict__ x_categ,
                                             const float* __restrict__ embed,
                                             float* __restrict__ x)
{
    size_t idx = (size_t)blockIdx.x * 256 + threadIdx.x;
    int row = (int)(idx >> 6), j = (int)(idx & 63);
    int tok = x_categ[row] + 2 + 100 * (row & 31);
    x[idx] = embed[(size_t)tok * 64 + j];
}

// ---------------------------------------------------------------------------
// LayerNorm: x fp32 -> h bf16. One wave per row (64 cols = 64 lanes).
// ---------------------------------------------------------------------------
__global__ __launch_bounds__(256) void k_ln(const float* __restrict__ x,
                                            const float* __restrict__ gam,
                                            const float* __restrict__ bet,
                                            __hip_bfloat16* __restrict__ h)
{
    const size_t row = (size_t)blockIdx.x * 4 + (threadIdx.x >> 6);
    const int lane = threadIdx.x & 63;
    float v = x[row * 64 + lane];
    float s = v, q = v * v;
#pragma unroll
    for (int m = 1; m < 64; m <<= 1) { s += __shfl_xor(s, m); q += __shfl_xor(q, m); }
    float mu = s * (1.f / 64.f);
    float var = q * (1.f / 64.f) - mu * mu;
    h[row * 64 + lane] = __float2bfloat16((v - mu) * rsqrtf(var + 1e-5f) * gam[lane] + bet[lane]);
}

// ---------------------------------------------------------------------------
// Fused qkv-projection + attention. 2 samples per block (128 threads, 2 waves,
// wave w owns sample w). All MFMA 16x16x32 bf16. LDS = 64,512 B (static-safe).
// ---------------------------------------------------------------------------
__global__ __launch_bounds__(128) void k_qkvattn(
    const __hip_bfloat16* __restrict__ h, const __hip_bfloat16* __restrict__ wqT,
    __hip_bfloat16* __restrict__ o)
{
    __shared__ __hip_bfloat16 ha[64][72];          // staged h rows
    __shared__ __hip_bfloat16 qs[64][136];         // q  [row][col] padded
    __shared__ __hip_bfloat16 kls[64][136];        // k
    __shared__ __hip_bfloat16 vt[2][8][16][32];    // V^T per (sample, head), XOR-swizzled
    __shared__ __hip_bfloat16 Ps[2][32][32];       // P per sample, XOR-swizzled

    const int tid = threadIdx.x;
    const int r0 = blockIdx.x * 64;
    const int w = tid >> 6, lane = tid & 63;
    const int lo = lane & 15, g = lane >> 4;

    // stage h block (64 rows x 64 bf16)
#pragma unroll
    for (int t = 0; t < 4; ++t) {
        int e = tid + t * 128;
        int row = e >> 3, seg = e & 7;
        *(uint4*)&ha[row][seg * 8] = *(const uint4*)&h[(size_t)(r0 + row) * 64 + seg * 8];
    }
    __syncthreads();

    // A fragments: wave's 32 rows, K=64 (2 k-steps)
    short8 af[2][2];
#pragma unroll
    for (int mt = 0; mt < 2; ++mt)
#pragma unroll
        for (int kk = 0; kk < 2; ++kk)
            af[mt][kk] = *(const short8*)&ha[w * 32 + mt * 16 + lo][kk * 32 + g * 8];

    // qkv GEMM: part 0=q,1=k,2=v; N=128 each; B-frags straight from global (L2)
#pragma unroll
    for (int part = 0; part < 3; ++part) {
        short8 bfr[8][2];
#pragma unroll
        for (int nt = 0; nt < 8; ++nt)
#pragma unroll
            for (int kk = 0; kk < 2; ++kk)
                bfr[nt][kk] = *(const short8*)&wqT[(size_t)(part * 128 + nt * 16 + lo) * 64 + kk * 32 + g * 8];
        f32x4 acc[2][8];
#pragma unroll
        for (int mt = 0; mt < 2; ++mt)
#pragma unroll
            for (int nt = 0; nt < 8; ++nt) acc[mt][nt] = f32x4{0.f, 0.f, 0.f, 0.f};
#pragma unroll
        for (int mt = 0; mt < 2; ++mt)
#pragma unroll
            for (int nt = 0; nt < 8; ++nt)
#pragma unroll
                for (int kk = 0; kk < 2; ++kk)
                    acc[mt][nt] = __builtin_amdgcn_mfma_f32_16x16x32_bf16(af[mt][kk], bfr[nt][kk], acc[mt][nt], 0, 0, 0);
#pragma unroll
        for (int mt = 0; mt < 2; ++mt)
#pragma unroll
            for (int nt = 0; nt < 8; ++nt)
#pragma unroll
                for (int rg = 0; rg < 4; ++rg) {
                    int rr = mt * 16 + g * 4 + rg;   // row within sample 0..31
                    int cc = nt * 16 + lo;           // col 0..127
                    __hip_bfloat16 val = __float2bfloat16(acc[mt][nt][rg]);
                    if (part == 0) qs[w * 32 + rr][cc] = val;
                    else if (part == 1) kls[w * 32 + rr][cc] = val;
                    else {
                        // store V transposed: vt[w][head][dh][j], swizzled 16B chunks
                        int hh = nt, dh = lo, j = rr;
                        int slot = (j >> 3) ^ ((dh >> 1) & 3);
                        vt[w][hh][dh][slot * 8 + (j & 7)] = val;
                    }
                }
    }
    // From here everything is wave-local (wave w only touches sample w's LDS).

    for (int hh = 0; hh < 8; ++hh) {
        short8 z8{};
        short8 aq0 = z8, aq1 = z8, bk0 = z8, bk1 = z8;
        if (g < 2) {   // K=32 MFMA, real dh occupies k 0..15, rest zero
            aq0 = *(const short8*)&qs[w * 32 + lo][hh * 16 + g * 8];
            aq1 = *(const short8*)&qs[w * 32 + 16 + lo][hh * 16 + g * 8];
            bk0 = *(const short8*)&kls[w * 32 + lo][hh * 16 + g * 8];
            bk1 = *(const short8*)&kls[w * 32 + 16 + lo][hh * 16 + g * 8];
        }
        f32x4 z4 = f32x4{0.f, 0.f, 0.f, 0.f};
        f32x4 S[2][2];
        S[0][0] = __builtin_amdgcn_mfma_f32_16x16x32_bf16(aq0, bk0, z4, 0, 0, 0);
        S[0][1] = __builtin_amdgcn_mfma_f32_16x16x32_bf16(aq0, bk1, z4, 0, 0, 0);
        S[1][0] = __builtin_amdgcn_mfma_f32_16x16x32_bf16(aq1, bk0, z4, 0, 0, 0);
        S[1][1] = __builtin_amdgcn_mfma_f32_16x16x32_bf16(aq1, bk1, z4, 0, 0, 0);
        // softmax per q-row: row lives on 16 lanes (lane&15 = j), jt in regs
#pragma unroll
        for (int qt = 0; qt < 2; ++qt)
#pragma unroll
            for (int rg = 0; rg < 4; ++rg) {
                float s0 = S[qt][0][rg] * 0.25f;
                float s1 = S[qt][1][rg] * 0.25f;
                float mx = fmaxf(s0, s1);
#pragma unroll
                for (int msk = 1; msk < 16; msk <<= 1) mx = fmaxf(mx, __shfl_xor(mx, msk));
                float e0 = __expf(s0 - mx), e1 = __expf(s1 - mx);
                float sm = e0 + e1;
#pragma unroll
                for (int msk = 1; msk < 16; msk <<= 1) sm += __shfl_xor(sm, msk);
                float rs = 1.f / sm;
                int q = qt * 16 + g * 4 + rg;
                int key = (q >> 1) & 3;
                int j0 = lo, j1 = 16 + lo;
                Ps[w][q][((((j0 >> 3) ^ key) << 3) | (j0 & 7))] = __float2bfloat16(e0 * rs);
                Ps[w][q][((((j1 >> 3) ^ key) << 3) | (j1 & 7))] = __float2bfloat16(e1 * rs);
            }
        // PV: O[q][dh] = sum_j P[q][j] V[j][dh]
        short8 bv = *(const short8*)&vt[w][hh][lo][(g ^ ((lo >> 1) & 3)) * 8];
#pragma unroll
        for (int qt = 0; qt < 2; ++qt) {
            int qrow = qt * 16 + lo;
            short8 ap = *(const short8*)&Ps[w][qrow][(g ^ ((qrow >> 1) & 3)) * 8];
            f32x4 ov = __builtin_amdgcn_mfma_f32_16x16x32_bf16(ap, bv, z4, 0, 0, 0);
#pragma unroll
            for (int rg = 0; rg < 4; ++rg)
                o[(size_t)(r0 + w * 32 + qt * 16 + g * 4 + rg) * 128 + hh * 16 + lo] = __float2bfloat16(ov[rg]);
        }
    }
}

// ---------------------------------------------------------------------------
// proj: x += o[NROW,128] @ woT^T + bo.  128-row tile, N=64, K=128.
// ---------------------------------------------------------------------------
__global__ __launch_bounds__(256) void k_proj(
    const __hip_bfloat16* __restrict__ o, const __hip_bfloat16* __restrict__ woT,
    const float* __restrict__ bo, float* __restrict__ x)
{
    __shared__ __hip_bfloat16 At[128][136];
    __shared__ __hip_bfloat16 Bt[64][136];
    const int tid = threadIdx.x;
    const size_t m0 = (size_t)blockIdx.x * 128;
    const int w = tid >> 6, lane = tid & 63, lo = lane & 15, g = lane >> 4;
#pragma unroll
    for (int t = 0; t < 8; ++t) {
        int e = tid + t * 256; int row = e >> 4, seg = e & 15;
        *(uint4*)&At[row][seg * 8] = *(const uint4*)&o[(m0 + row) * 128 + seg * 8];
    }
#pragma unroll
    for (int t = 0; t < 4; ++t) {
        int e = tid + t * 256; int row = e >> 4, seg = e & 15;
        *(uint4*)&Bt[row][seg * 8] = *(const uint4*)&woT[(size_t)row * 128 + seg * 8];
    }
    __syncthreads();
    f32x4 acc[2][4];
#pragma unroll
    for (int mt = 0; mt < 2; ++mt)
#pragma unroll
        for (int nt = 0; nt < 4; ++nt) acc[mt][nt] = f32x4{0.f, 0.f, 0.f, 0.f};
#pragma unroll
    for (int kk = 0; kk < 4; ++kk) {
        short8 a[2], b[4];
#pragma unroll
        for (int mt = 0; mt < 2; ++mt) a[mt] = *(const short8*)&At[w * 32 + mt * 16 + lo][kk * 32 + g * 8];
#pragma unroll
        for (int nt = 0; nt < 4; ++nt) b[nt] = *(const short8*)&Bt[nt * 16 + lo][kk * 32 + g * 8];
#pragma unroll
        for (int mt = 0; mt < 2; ++mt)
#pragma unroll
            for (int nt = 0; nt < 4; ++nt)
                acc[mt][nt] = __builtin_amdgcn_mfma_f32_16x16x32_bf16(a[mt], b[nt], acc[mt][nt], 0, 0, 0);
    }
#pragma unroll
    for (int mt = 0; mt < 2; ++mt)
#pragma unroll
        for (int nt = 0; nt < 4; ++nt)
#pragma unroll
            for (int rg = 0; rg < 4; ++rg) {
                size_t row = m0 + w * 32 + mt * 16 + g * 4 + rg;
                int col = nt * 16 + lo;
                x[row * 64 + col] += acc[mt][nt][rg] + bo[col];
            }
}

// ---------------------------------------------------------------------------
// ff1 + geglu: p = (h@W1a + b_a) * gelu(h@W1g + b_g).  Grid (m, nb=0..3).
// ---------------------------------------------------------------------------
__global__ __launch_bounds__(256) void k_ff1(
    const __hip_bfloat16* __restrict__ h, const __hip_bfloat16* __restrict__ w1T,
    const float* __restrict__ b1, __hip_bfloat16* __restrict__ p)
{
    __shared__ __hip_bfloat16 At[128][72];
    __shared__ __hip_bfloat16 Ba[64][72];
    __shared__ __hip_bfloat16 Bg[64][72];
    const int tid = threadIdx.x;
    const size_t m0 = (size_t)blockIdx.x * 128;
    const int nb = blockIdx.y;
    const int w = tid >> 6, lane = tid & 63, lo = lane & 15, g = lane >> 4;
    const int wr = w >> 1, wc = w & 1;
#pragma unroll
    for (int t = 0; t < 4; ++t) {
        int e = tid + t * 256; int row = e >> 3, seg = e & 7;
        *(uint4*)&At[row][seg * 8] = *(const uint4*)&h[(m0 + row) * 64 + seg * 8];
    }
#pragma unroll
    for (int t = 0; t < 2; ++t) {
        int e = tid + t * 256; int row = e >> 3, seg = e & 7;
        *(uint4*)&Ba[row][seg * 8] = *(const uint4*)&w1T[(size_t)(nb * 64 + row) * 64 + seg * 8];
        *(uint4*)&Bg[row][seg * 8] = *(const uint4*)&w1T[(size_t)(256 + nb * 64 + row) * 64 + seg * 8];
    }
    __syncthreads();
    f32x4 aa[4][2], ag[4][2];
#pragma unroll
    for (int mt = 0; mt < 4; ++mt)
#pragma unroll
        for (int nt = 0; nt < 2; ++nt) { aa[mt][nt] = f32x4{0.f,0.f,0.f,0.f}; ag[mt][nt] = f32x4{0.f,0.f,0.f,0.f}; }
#pragma unroll
    for (int kk = 0; kk < 2; ++kk) {
        short8 a[4], ba[2], bg2[2];
#pragma unroll
        for (int mt = 0; mt < 4; ++mt) a[mt] = *(const short8*)&At[wr * 64 + mt * 16 + lo][kk * 32 + g * 8];
#pragma unroll
        for (int nt = 0; nt < 2; ++nt) {
            ba[nt]  = *(const short8*)&Ba[wc * 32 + nt * 16 + lo][kk * 32 + g * 8];
            bg2[nt] = *(const short8*)&Bg[wc * 32 + nt * 16 + lo][kk * 32 + g * 8];
        }
#pragma unroll
        for (int mt = 0; mt < 4; ++mt)
#pragma unroll
            for (int nt = 0; nt < 2; ++nt) {
                aa[mt][nt] = __builtin_amdgcn_mfma_f32_16x16x32_bf16(a[mt], ba[nt],  aa[mt][nt], 0, 0, 0);
                ag[mt][nt] = __builtin_amdgcn_mfma_f32_16x16x32_bf16(a[mt], bg2[nt], ag[mt][nt], 0, 0, 0);
            }
    }
#pragma unroll
    for (int mt = 0; mt < 4; ++mt)
#pragma unroll
        for (int nt = 0; nt < 2; ++nt)
#pragma unroll
            for (int rg = 0; rg < 4; ++rg) {
                size_t row = m0 + wr * 64 + mt * 16 + g * 4 + rg;
                int colp = nb * 64 + wc * 32 + nt * 16 + lo;
                float a = aa[mt][nt][rg] + b1[colp];
                float gg2 = ag[mt][nt][rg] + b1[256 + colp];
                float gl = 0.5f * gg2 * (1.f + erff(gg2 * 0.70710678118654752f));
                p[row * 256 + colp] = __float2bfloat16(a * gl);
            }
}

// ---------------------------------------------------------------------------
// ff2: x += p[NROW,256] @ w2T^T + b2.  K=256 in 2 chunks of 128.
// ---------------------------------------------------------------------------
__global__ __launch_bounds__(256) void k_ff2(
    const __hip_bfloat16* __restrict__ p, const __hip_bfloat16* __restrict__ w2T,
    const float* __restrict__ b2, float* __restrict__ x)
{
    __shared__ __hip_bfloat16 At[128][136];
    __shared__ __hip_bfloat16 Bt[64][136];
    const int tid = threadIdx.x;
    const size_t m0 = (size_t)blockIdx.x * 128;
    const int w = tid >> 6, lane = tid & 63, lo = lane & 15, g = lane >> 4;
    f32x4 acc[2][4];
#pragma unroll
    for (int mt = 0; mt < 2; ++mt)
#pragma unroll
        for (int nt = 0; nt < 4; ++nt) acc[mt][nt] = f32x4{0.f, 0.f, 0.f, 0.f};
    for (int kt = 0; kt < 2; ++kt) {
        if (kt) __syncthreads();
#pragma unroll
        for (int t = 0; t < 8; ++t) {
            int e = tid + t * 256; int row = e >> 4, seg = e & 15;
            *(uint4*)&At[row][seg * 8] = *(const uint4*)&p[(m0 + row) * 256 + kt * 128 + seg * 8];
        }
#pragma unroll
        for (int t = 0; t < 4; ++t) {
            int e = tid + t * 256; int row = e >> 4, seg = e & 15;
            *(uint4*)&Bt[row][seg * 8] = *(const uint4*)&w2T[(size_t)row * 256 + kt * 128 + seg * 8];
        }
        __syncthreads();
#pragma unroll
        for (int kk = 0; kk < 4; ++kk) {
            short8 a[2], b[4];
#pragma unroll
            for (int mt = 0; mt < 2; ++mt) a[mt] = *(const short8*)&At[w * 32 + mt * 16 + lo][kk * 32 + g * 8];
#pragma unroll
            for (int nt = 0; nt < 4; ++nt) b[nt] = *(const short8*)&Bt[nt * 16 + lo][kk * 32 + g * 8];
#pragma unroll
            for (int mt = 0; mt < 2; ++mt)
#pragma unroll
                for (int nt = 0; nt < 4; ++nt)
                    acc[mt][nt] = __builtin_amdgcn_mfma_f32_16x16x32_bf16(a[mt], b[nt], acc[mt][nt], 0, 0, 0);
        }
    }
#pragma unroll
    for (int mt = 0; mt < 2; ++mt)
#pragma unroll
        for (int nt = 0; nt < 4; ++nt)
#pragma unroll
            for (int rg = 0; rg < 4; ++rg) {
                size_t row = m0 + w * 32 + mt * 16 + g * 4 + rg;
                int col = nt * 16 + lo;
                x[row * 64 + col] += acc[mt][nt][rg] + b2[col];
            }
}

// ---------------------------------------------------------------------------
// cast x -> Acat cols 0..2047 bf16
// ---------------------------------------------------------------------------
__global__ __launch_bounds__(256) void k_cast(const float* __restrict__ x,
                                              __hip_bfloat16* __restrict__ Acat)
{
    size_t idx = (size_t)blockIdx.x * 256 + threadIdx.x;
    int b = (int)(idx >> 11), c = (int)(idx & 2047);
    Acat[(size_t)b * KTOT + c] = __float2bfloat16(x[idx]);
}

// ---------------------------------------------------------------------------
// BatchNorm1d (batch stats), one block per feature column.
// ---------------------------------------------------------------------------
__global__ __launch_bounds__(256) void k_bn(
    const float* __restrict__ x_cont, const float* __restrict__ bn_g, const float* __restrict__ bn_b,
    float* __restrict__ normed, __hip_bfloat16* __restrict__ Acat)
{
    const int c = blockIdx.x;
    const int tid = threadIdx.x;
    float sum = 0.f, sq = 0.f;
    for (int rr = tid; rr < B_; rr += 256) { float v = x_cont[rr * NCONT + c]; sum += v; sq += v * v; }
    __shared__ float ssum[256], ssq[256];
    ssum[tid] = sum; ssq[tid] = sq;
    __syncthreads();
    for (int st = 128; st > 0; st >>= 1) {
        if (tid < st) { ssum[tid] += ssum[tid + st]; ssq[tid] += ssq[tid + st]; }
        __syncthreads();
    }
    float mu  = ssum[0] * (1.f / B_);
    float var = ssq[0] * (1.f / B_) - mu * mu;
    float ri  = rsqrtf(var + 1e-5f);
    float gg = bn_g[c], bb = bn_b[c];
    for (int rr = tid; rr < B_; rr += 256) {
        float v = (x_cont[rr * NCONT + c] - mu) * ri * gg + bb;
        normed[rr * NCONT + c] = v;
        Acat[(size_t)rr * KTOT + CATF + c] = __float2bfloat16(v);
    }
}

// ---------------------------------------------------------------------------
// g0_w [2112,2048] fp32 -> WT [2048,2112] bf16 (k-contiguous)
// ---------------------------------------------------------------------------
__global__ __launch_bounds__(256) void k_transpose(
    const float* __restrict__ W, __hip_bfloat16* __restrict__ WT)
{
    __shared__ float tile[64][65];
    const int n0 = blockIdx.x * 64, k0 = blockIdx.y * 64;
    const int tid = threadIdx.x;
    for (int e = tid; e < 64 * 16; e += 256) {
        int rr = e >> 4, c4 = e & 15;
        float4 v = *(const float4*)&W[(size_t)(k0 + rr) * CATF + n0 + c4 * 4];
        tile[rr][c4 * 4 + 0] = v.x; tile[rr][c4 * 4 + 1] = v.y;
        tile[rr][c4 * 4 + 2] = v.z; tile[rr][c4 * 4 + 3] = v.w;
    }
    __syncthreads();
    for (int e = tid; e < 64 * 32; e += 256) {
        int n = e >> 5, kp = e & 31;
        __hip_bfloat16 h0 = __float2bfloat16(tile[kp * 2 + 0][n]);
        __hip_bfloat16 h1 = __float2bfloat16(tile[kp * 2 + 1][n]);
        unsigned u = ((unsigned)(*(unsigned short*)&h1) << 16) | (unsigned)(*(unsigned short*)&h0);
        *(unsigned*)&WT[(size_t)(n0 + n) * KTOT + k0 + kp * 2] = u;
    }
}

// ---------------------------------------------------------------------------
// G = relu(Acat[4096,2112] @ g0_w + g0_b), bf16 MFMA, 128x128 tiles
// ---------------------------------------------------------------------------
__global__ __launch_bounds__(256) void k_gemm_g0(
    const __hip_bfloat16* __restrict__ Acat, const __hip_bfloat16* __restrict__ WT,
    const float* __restrict__ g0_b, __hip_bfloat16* __restrict__ G)
{
    __shared__ unsigned short At[128][40];
    __shared__ unsigned short Bt[128][40];
    const int tid = threadIdx.x;
    const int m0 = blockIdx.y * 128, n0 = blockIdx.x * 128;
    const int w = tid >> 6, lane = tid & 63;
    const int wr = w >> 1, wc = w & 1;

    f32x4 acc[4][4];
#pragma unroll
    for (int mi = 0; mi < 4; ++mi)
#pragma unroll
        for (int ni = 0; ni < 4; ++ni) acc[mi][ni] = f32x4{0.f, 0.f, 0.f, 0.f};

    const int row_a = wr * 64 + (lane & 15);
    const int row_b = wc * 64 + (lane & 15);
    const int koff = (lane >> 4) * 8;

    for (int kt = 0; kt < KTOT / 32; ++kt) {
        const int k0 = kt * 32;
        for (int e = tid; e < 512; e += 256) {
            int rr = e >> 2, seg = e & 3;
            *(uint4*)&At[rr][seg * 8] = *(const uint4*)&Acat[(size_t)(m0 + rr) * KTOT + k0 + seg * 8];
        }
        for (int e = tid; e < 512; e += 256) {
            int rr = e >> 2, seg = e & 3;
            *(uint4*)&Bt[rr][seg * 8] = *(const uint4*)&WT[(size_t)(n0 + rr) * KTOT + k0 + seg * 8];
        }
        __syncthreads();
        short8 af[4], bfr[4];
#pragma unroll
        for (int mi = 0; mi < 4; ++mi) af[mi] = *(const short8*)&At[row_a + mi * 16][koff];
#pragma unroll
        for (int ni = 0; ni < 4; ++ni) bfr[ni] = *(const short8*)&Bt[row_b + ni * 16][koff];
#pragma unroll
        for (int mi = 0; mi < 4; ++mi)
#pragma unroll
            for (int ni = 0; ni < 4; ++ni)
                acc[mi][ni] = __builtin_amdgcn_mfma_f32_16x16x32_bf16(af[mi], bfr[ni], acc[mi][ni], 0, 0, 0);
        __syncthreads();
    }

#pragma unroll
    for (int mi = 0; mi < 4; ++mi)
#pragma unroll
        for (int ni = 0; ni < 4; ++ni)
#pragma unroll
            for (int reg = 0; reg < 4; ++reg) {
                int row = m0 + wr * 64 + mi * 16 + (lane >> 4) * 4 + reg;
                int col = n0 + wc * 64 + ni * 16 + (lane & 15);
                float v = acc[mi][ni][reg] + g0_b[col];
                G[(size_t)row * CATF + col] = __float2bfloat16(fmaxf(v, 0.f));
            }
}

// ---------------------------------------------------------------------------
// y1 = flat_categ @ y1_w + y1_b.  MFMA, M=4096 N=64 K=2048, 128-row blocks.
// ---------------------------------------------------------------------------
__global__ __launch_bounds__(256) void k_y1v2(
    const __hip_bfloat16* __restrict__ Acat, const __hip_bfloat16* __restrict__ y1T,
    const float* __restrict__ y1_b, float* __restrict__ y1)
{
    __shared__ __hip_bfloat16 At[128][136];
    __shared__ __hip_bfloat16 Bt[64][136];
    const int tid = threadIdx.x;
    const size_t m0 = (size_t)blockIdx.x * 128;
    const int w = tid >> 6, lane = tid & 63, lo = lane & 15, g = lane >> 4;
    f32x4 acc[2][4];
#pragma unroll
    for (int mt = 0; mt < 2; ++mt)
#pragma unroll
        for (int nt = 0; nt < 4; ++nt) acc[mt][nt] = f32x4{0.f, 0.f, 0.f, 0.f};
    for (int kt = 0; kt < 16; ++kt) {
        if (kt) __syncthreads();
#pragma unroll
        for (int t = 0; t < 8; ++t) {
            int e = tid + t * 256; int row = e >> 4, seg = e & 15;
            *(uint4*)&At[row][seg * 8] = *(const uint4*)&Acat[(m0 + row) * KTOT + kt * 128 + seg * 8];
        }
#pragma unroll
        for (int t = 0; t < 4; ++t) {
            int e = tid + t * 256; int row = e >> 4, seg = e & 15;
            *(uint4*)&Bt[row][seg * 8] = *(const uint4*)&y1T[(size_t)row * 2048 + kt * 128 + seg * 8];
        }
        __syncthreads();
#pragma unroll
        for (int kk = 0; kk < 4; ++kk) {
            short8 a[2], b[4];
#pragma unroll
            for (int mt = 0; mt < 2; ++mt) a[mt] = *(const short8*)&At[w * 32 + mt * 16 + lo][kk * 32 + g * 8];
#pragma unroll
            for (int nt = 0; nt < 4; ++nt) b[nt] = *(const short8*)&Bt[nt * 16 + lo][kk * 32 + g * 8];
#pragma unroll
            for (int mt = 0; mt < 2; ++mt)
#pragma unroll
                for (int nt = 0; nt < 4; ++nt)
                    acc[mt][nt] = __builtin_amdgcn_mfma_f32_16x16x32_bf16(a[mt], b[nt], acc[mt][nt], 0, 0, 0);
        }
    }
#pragma unroll
    for (int mt = 0; mt < 2; ++mt)
#pragma unroll
        for (int nt = 0; nt < 4; ++nt)
#pragma unroll
            for (int rg = 0; rg < 4; ++rg) {
                size_t row = m0 + w * 32 + mt * 16 + g * 4 + rg;
                int col = nt * 16 + lo;
                y1[row * 64 + col] = acc[mt][nt][rg] + y1_b[col];
            }
}

// ---------------------------------------------------------------------------
// H = G * (normed @ h0_w), in-place over G. MFMA, M=4096 N=2048 K=64.
// A = Acat cols 2048..2111 (bf16 normed), B = h0T [2048][64].
// ---------------------------------------------------------------------------
__global__ __launch_bounds__(256) void k_H2(
    const __hip_bfloat16* __restrict__ Acat, const __hip_bfloat16* __restrict__ h0T,
    __hip_bfloat16* __restrict__ G)
{
    __shared__ __hip_bfloat16 At[128][72];
    const int tid = threadIdx.x;
    const int m0 = blockIdx.y * 128, n0 = blockIdx.x * 128;
    const int w = tid >> 6, lane = tid & 63, lo = lane & 15, g = lane >> 4;
    const int wr = w >> 1, wc = w & 1;
#pragma unroll
    for (int t = 0; t < 4; ++t) {
        int e = tid + t * 256; int row = e >> 3, seg = e & 7;
        *(uint4*)&At[row][seg * 8] = *(const uint4*)&Acat[(size_t)(m0 + row) * KTOT + CATF + seg * 8];
    }
    __syncthreads();
    f32x4 acc[4][4];
#pragma unroll
    for (int mt = 0; mt < 4; ++mt)
#pragma unroll
        for (int nt = 0; nt < 4; ++nt) acc[mt][nt] = f32x4{0.f, 0.f, 0.f, 0.f};
#pragma unroll
    for (int kk = 0; kk < 2; ++kk) {
        short8 a[4], b[4];
#pragma unroll
        for (int mt = 0; mt < 4; ++mt) a[mt] = *(const short8*)&At[wr * 64 + mt * 16 + lo][kk * 32 + g * 8];
#pragma unroll
        for (int nt = 0; nt < 4; ++nt)
            b[nt] = *(const short8*)&h0T[(size_t)(n0 + wc * 64 + nt * 16 + lo) * 64 + kk * 32 + g * 8];
#pragma unroll
        for (int mt = 0; mt < 4; ++mt)
#pragma unroll
            for (int nt = 0; nt < 4; ++nt)
                acc[mt][nt] = __builtin_amdgcn_mfma_f32_16x16x32_bf16(a[mt], b[nt], acc[mt][nt], 0, 0, 0);
    }
#pragma unroll
    for (int mt = 0; mt < 4; ++mt)
#pragma unroll
        for (int nt = 0; nt < 4; ++nt)
#pragma unroll
            for (int rg = 0; rg < 4; ++rg) {
                size_t row = (size_t)m0 + wr * 64 + mt * 16 + g * 4 + rg;
                int col = n0 + wc * 64 + nt * 16 + lo;
                size_t offo = row * CATF + col;
                G[offo] = __float2bfloat16(bf2f(G[offo]) * acc[mt][nt][rg]);
            }
}

// ---------------------------------------------------------------------------
// Final: norms, alpha, c0/c1 combine, fc dot, sigmoid. One block per row.
// ---------------------------------------------------------------------------
__global__ __launch_bounds__(256) void k_final(
    const __hip_bfloat16* __restrict__ Acat, const __hip_bfloat16* __restrict__ H,
    const float* __restrict__ normed, const float* __restrict__ y1,
    const float* __restrict__ g1_w, const float* __restrict__ g1_b, const float* __restrict__ h1_w,
    const float* __restrict__ fc_w, const float* __restrict__ fc_b,
    float* __restrict__ out)
{
    const int b = blockIdx.x;
    const int tid = threadIdx.x;
    const __hip_bfloat16* xrow = Acat + (size_t)b * KTOT;
    const __hip_bfloat16* hrow = H + (size_t)b * CATF;

    __shared__ float r1[256], r2[256];
    float sx = 0.f, sh = 0.f;
    for (int n = tid; n < CATF; n += 256) {
        float xv = bf2f(xrow[n]); sx += xv * xv;
        float hv = bf2f(hrow[n]); sh += hv * hv;
    }
    r1[tid] = sx; r2[tid] = sh;
    __syncthreads();
    for (int st = 128; st > 0; st >>= 1) {
        if (tid < st) { r1[tid] += r1[tid + st]; r2[tid] += r2[tid + st]; }
        __syncthreads();
    }
    float alpha0 = fminf(fmaxf(sqrtf(r1[0]) / (sqrtf(r2[0]) + 1e-12f) * 0.2f, 0.f), 1.f);
    __syncthreads();

    float pd = 0.f;
    for (int n = tid; n < CATF; n += 256) {
        float c0 = bf2f(xrow[n]) + alpha0 * bf2f(hrow[n]);
        pd += c0 * fc_w[n];
    }
    r1[tid] = pd;
    __syncthreads();
    for (int st = 128; st > 0; st >>= 1) {
        if (tid < st) r1[tid] += r1[tid + st];
        __syncthreads();
    }
    float dot0 = r1[0];

    __shared__ float ny[128];
    __shared__ float c1dot;
    if (tid < 64) ny[tid] = normed[b * NCONT + tid];
    else if (tid < 128) ny[tid] = y1[b * NCONT + tid - 64];
    __syncthreads();

    if (tid < 64) {
        const int j = tid;
        float g = g1_b[j];
        for (int k = 0; k < 128; ++k) g += ny[k] * g1_w[k * 64 + j];
        g = fmaxf(g, 0.f);
        float hv = 0.f;
        for (int k = 0; k < 64; ++k) hv += ny[64 + k] * h1_w[k * 64 + j];
        float H1 = g * hv;
        float nj = ny[j];
        float snx = nj * nj, snh = H1 * H1;
        for (int m = 1; m < 64; m <<= 1) { snx += __shfl_xor(snx, m, 64); snh += __shfl_xor(snh, m, 64); }
        float a1 = fminf(fmaxf(sqrtf(snx) / (sqrtf(snh) + 1e-12f) * 0.2f, 0.f), 1.f);
        float d1 = (nj + a1 * H1) * fc_w[CATF + j];
        for (int m = 1; m < 64; m <<= 1) d1 += __shfl_xor(d1, m, 64);
        if (tid == 0) c1dot = d1;
    }
    __syncthreads();
    if (tid == 0) {
        float logit = dot0 + c1dot + fc_b[0];
        out[b] = 1.f / (1.f + expf(-logit));
    }
}

// ---------------------------------------------------------------------------
extern "C" void kernel_launch(void* const* d_in, const int* in_sizes, int n_in,
                              void* d_out, int out_size, void* d_ws, size_t ws_size,
                              hipStream_t stream)
{
    const int*   x_categ = (const int*)d_in[0];
    const float* x_cont  = (const float*)d_in[1];
    const float* embed   = (const float*)d_in[2];
    const float* ln1_g   = (const float*)d_in[3];
    const float* ln1_b   = (const float*)d_in[4];
    const float* wqkv    = (const float*)d_in[5];
    const float* wo      = (const float*)d_in[6];
    const float* bo      = (const float*)d_in[7];
    const float* ln2_g   = (const float*)d_in[8];
    const float* ln2_b   = (const float*)d_in[9];
    const float* wff1    = (const float*)d_in[10];
    const float* bff1    = (const float*)d_in[11];
    const float* wff2    = (const float*)d_in[12];
    const float* bff2    = (const float*)d_in[13];
    const float* bn_g    = (const float*)d_in[14];
    const float* bn_b    = (const float*)d_in[15];
    const float* g0_w    = (const float*)d_in[16];
    const float* g0_b    = (const float*)d_in[17];
    const float* h0_w    = (const float*)d_in[18];
    const float* y1_w    = (const float*)d_in[19];
    const float* y1_b    = (const float*)d_in[20];
    const float* g1_w    = (const float*)d_in[21];
    const float* g1_b    = (const float*)d_in[22];
    const float* h1_w    = (const float*)d_in[23];
    const float* fc_w    = (const float*)d_in[24];
    const float* fc_b    = (const float*)d_in[25];

    // ---- workspace layout (lifetime-aliased, total ~119 MB) ----
    char* ws = (char*)d_ws;
    size_t off = 0;
    auto alloc = [&](size_t bytes) { void* pp = ws + off; off += (bytes + 255) & ~255ULL; return pp; };
    float*          x    = (float*)alloc((size_t)NROW * 64 * 4);             // 33.55 MB
    __hip_bfloat16* h    = (__hip_bfloat16*)alloc((size_t)NROW * 64 * 2);    // 16.78 MB (tail: Acat start)
    __hip_bfloat16* wqT  = (__hip_bfloat16*)alloc((size_t)DEPTH * 384 * 64 * 2);
    __hip_bfloat16* woT  = (__hip_bfloat16*)alloc((size_t)DEPTH * 64 * 128 * 2);
    __hip_bfloat16* w1T  = (__hip_bfloat16*)alloc((size_t)DEPTH * 512 * 64 * 2);
    __hip_bfloat16* w2T  = (__hip_bfloat16*)alloc((size_t)DEPTH * 64 * 256 * 2);
    __hip_bfloat16* h0T  = (__hip_bfloat16*)alloc((size_t)CATF * 64 * 2);    // survives loop
    __hip_bfloat16* y1T  = (__hip_bfloat16*)alloc((size_t)CATF * 64 * 2);    // survives loop
    __hip_bfloat16* big  = (__hip_bfloat16*)alloc((size_t)NROW * 256 * 2);   // 67.1 MB: o/p in loop
    __hip_bfloat16* o    = big;
    __hip_bfloat16* p    = big;
    // tail aliases:
    //  Acat (17,301,504 B) overlays h + wqT + woT + first part of w1T (all dead post-loop;
    //  h0T/y1T start at h+17,760,256 > Acat end, untouched).
    __hip_bfloat16* Acat = h;
    //  WT/G/normed/y1 live inside big (27.5 MB < 67.1 MB; o/p dead post-loop).
    char* bigc = (char*)big;
    __hip_bfloat16* WT   = (__hip_bfloat16*)bigc;                            //  8,650,752 B
    __hip_bfloat16* G    = (__hip_bfloat16*)(bigc + 8650752);                // 16,777,216 B (H in-place)
    float*          norm = (float*)(bigc + 8650752 + 16777216);              //  1,048,576 B
    float*          y1v  = (float*)(bigc + 8650752 + 16777216 + 1048576);    //  1,048,576 B

    // weight prep
    k_wT<<<576, 256, 0, stream>>>(wqkv, wqT, 64, 384);
    k_wT<<<192, 256, 0, stream>>>(wo,   woT, 128, 64);
    k_wT<<<768, 256, 0, stream>>>(wff1, w1T, 64, 512);
    k_wT<<<384, 256, 0, stream>>>(wff2, w2T, 256, 64);
    k_wT<<<512, 256, 0, stream>>>(h0_w, h0T, 64, 2048);
    k_wT<<<512, 256, 0, stream>>>(y1_w, y1T, 2048, 64);

    k_emb<<<NROW * 64 / 256, 256, 0, stream>>>(x_categ, embed, x);

    for (int d = 0; d < DEPTH; ++d) {
        k_ln<<<NROW / 4, 256, 0, stream>>>(x, ln1_g + d * 64, ln1_b + d * 64, h);
        k_qkvattn<<<NROW / 64, 128, 0, stream>>>(h, wqT + (size_t)d * 384 * 64, o);
        k_proj<<<NROW / 128, 256, 0, stream>>>(o, woT + (size_t)d * 64 * 128, bo + d * 64, x);
        k_ln<<<NROW / 4, 256, 0, stream>>>(x, ln2_g + d * 64, ln2_b + d * 64, h);
        k_ff1<<<dim3(NROW / 128, 4), 256, 0, stream>>>(h, w1T + (size_t)d * 512 * 64, bff1 + d * 512, p);
        k_ff2<<<NROW / 128, 256, 0, stream>>>(p, w2T + (size_t)d * 64 * 256, bff2 + d * 64, x);
    }

    k_cast<<<B_ * CATF / 256, 256, 0, stream>>>(x, Acat);
    k_bn<<<NCONT, 256, 0, stream>>>(x_cont, bn_g, bn_b, norm, Acat);
    k_transpose<<<dim3(CATF / 64, KTOT / 64), 256, 0, stream>>>(g0_w, WT);
    k_gemm_g0<<<dim3(CATF / 128, B_ / 128), 256, 0, stream>>>(Acat, WT, g0_b, G);
    k_y1v2<<<B_ / 128, 256, 0, stream>>>(Acat, y1T, y1_b, y1v);
    k_H2<<<dim3(CATF / 128, B_ / 128), 256, 0, stream>>>(Acat, h0T, G);
    k_final<<<B_, 256, 0, stream>>>(Acat, G, norm, y1v, g1_w, g1_b, h1_w, fc_w, fc_b, (float*)d_out);
}

// Round 4
// 1058.595 us; speedup vs baseline: 16.9555x; 1.3931x over previous
//
#include <hip/hip_runtime.h>
#include <hip/hip_bf16.h>

#define B_    4096
#define NC    32
#define DIM   64
#define INNER 128
#define HEADS 8
#define DH    16
#define DEPTH 6
#define NCONT 64
#define CATF  2048
#define KTOT  2112
#define NROW  (B_ * NC)          // 131072 token rows

typedef __attribute__((ext_vector_type(8))) short short8;
typedef __attribute__((ext_vector_type(4))) float f32x4;

__device__ __forceinline__ float bf2f(__hip_bfloat16 h) { return __bfloat162float(h); }

// ---------------------------------------------------------------------------
// Generic weight transpose+cast: W [D][K][N] fp32 -> WT [D][N][K] bf16
// ---------------------------------------------------------------------------
__global__ __launch_bounds__(256) void k_wT(const float* __restrict__ W,
                                            __hip_bfloat16* __restrict__ WT,
                                            int K, int N)
{
    size_t idx = (size_t)blockIdx.x * 256 + threadIdx.x;
    int kn = K * N;
    int d = (int)(idx / kn), rem = (int)(idx % kn);
    int n = rem / K, k = rem % K;
    WT[idx] = __float2bfloat16(W[(size_t)d * kn + (size_t)k * N + n]);
}

// ---------------------------------------------------------------------------
// THE transformer megakernel: emb + 6 layers + Acat cast. 2 samples/block,
// 128 threads (2 waves, wave w = sample w). Zero __syncthreads (all LDS
// regions are wave-private). LDS = 49.7 KB -> 3 blocks/CU (6 waves/CU).
// ---------------------------------------------------------------------------
__global__ __launch_bounds__(128) void k_former(
    const int* __restrict__ x_categ, const float* __restrict__ embed,
    const float* __restrict__ ln1_g, const float* __restrict__ ln1_b,
    const __hip_bfloat16* __restrict__ wqT, const __hip_bfloat16* __restrict__ woT,
    const float* __restrict__ bo,
    const float* __restrict__ ln2_g, const float* __restrict__ ln2_b,
    const __hip_bfloat16* __restrict__ w1T, const float* __restrict__ bff1,
    const __hip_bfloat16* __restrict__ w2T, const float* __restrict__ bff2,
    __hip_bfloat16* __restrict__ Acat)
{
    __shared__ float xs[64][68];                 // residual fp32 (17.4 KB)
    __shared__ __hip_bfloat16 U[64][136];        // union: ha1 / os / ha2 / pg (17.4 KB)
    __shared__ __hip_bfloat16 qh[64][40];        // per-head q, cols 16..31 zero (5.1 KB)
    __shared__ __hip_bfloat16 kh[64][40];        // per-head k (5.1 KB)
    __shared__ __hip_bfloat16 vth[2][16][40];    // per-head V^T [dh][token] (2.5 KB)
    __shared__ __hip_bfloat16 Ps[2][32][32];     // P, XOR-swizzled (2 KB)

    const int tid = threadIdx.x;
    const int w = tid >> 6, lane = tid & 63;
    const int lo = lane & 15, g = lane >> 4;
    const int r0 = blockIdx.x * 64;
    const f32x4 z4 = f32x4{0.f, 0.f, 0.f, 0.f};

    // zero qh/kh cols 16..31 once (zero-padding for the K=32 QK^T MFMA)
    for (int i = lane; i < 32 * 16; i += 64) {
        int r = w * 32 + (i >> 4), c = 16 + (i & 15);
        qh[r][c] = __float2bfloat16(0.f);
        kh[r][c] = __float2bfloat16(0.f);
    }

    // embedding gather -> xs (wave-local: 2 lanes/row)
    {
        int r = w * 32 + (lane >> 1), half = lane & 1;
        int grow = r0 + r;
        int tok = x_categ[grow] + 2 + 100 * (grow & 31);
        const float4* src = (const float4*)(embed + (size_t)tok * 64 + half * 32);
#pragma unroll
        for (int q4 = 0; q4 < 8; ++q4) {
            float4 v = src[q4];
            xs[r][half * 32 + q4 * 4 + 0] = v.x; xs[r][half * 32 + q4 * 4 + 1] = v.y;
            xs[r][half * 32 + q4 * 4 + 2] = v.z; xs[r][half * 32 + q4 * 4 + 3] = v.w;
        }
    }

    // LayerNorm helper: xs -> U (bf16), wave-local (2 lanes/row)
    auto layernorm = [&](const float* gam, const float* bet) {
        int r = w * 32 + (lane >> 1), half = lane & 1;
        float s = 0.f, qq = 0.f;
#pragma unroll
        for (int j = 0; j < 32; ++j) { float v = xs[r][half * 32 + j]; s += v; qq += v * v; }
        s += __shfl_xor(s, 1); qq += __shfl_xor(qq, 1);
        float mu = s * (1.f / 64.f);
        float var = qq * (1.f / 64.f) - mu * mu;
        float ri = rsqrtf(var + 1e-5f);
#pragma unroll
        for (int j = 0; j < 32; j += 2) {
            int c = half * 32 + j;
            __hip_bfloat16 h0 = __float2bfloat16((xs[r][c] - mu) * ri * gam[c] + bet[c]);
            __hip_bfloat16 h1 = __float2bfloat16((xs[r][c + 1] - mu) * ri * gam[c + 1] + bet[c + 1]);
            unsigned u = ((unsigned)(*(unsigned short*)&h1) << 16) | (unsigned)(*(unsigned short*)&h0);
            *(unsigned*)&U[r][c] = u;
        }
    };

#pragma unroll 1
    for (int d = 0; d < DEPTH; ++d) {
        const __hip_bfloat16* wq_d = wqT + (size_t)d * 384 * 64;
        const __hip_bfloat16* wo_d = woT + (size_t)d * 64 * 128;
        const __hip_bfloat16* w1_d = w1T + (size_t)d * 512 * 64;
        const __hip_bfloat16* w2_d = w2T + (size_t)d * 64 * 256;

        // ---- LN1 ----
        layernorm(ln1_g + d * 64, ln1_b + d * 64);

        // A-frags of h (persist across heads)
        short8 af[2][2];
#pragma unroll
        for (int mt = 0; mt < 2; ++mt)
#pragma unroll
            for (int kk = 0; kk < 2; ++kk)
                af[mt][kk] = *(const short8*)&U[w * 32 + mt * 16 + lo][kk * 32 + g * 8];

        // ---- attention, per head ----
        for (int hh = 0; hh < HEADS; ++hh) {
            // qkv for this head (N=16 per part)
            f32x4 aq[2] = {z4, z4}, ak[2] = {z4, z4}, av[2] = {z4, z4};
#pragma unroll
            for (int kk = 0; kk < 2; ++kk) {
                short8 bq  = *(const short8*)&wq_d[(size_t)(hh * 16 + lo) * 64 + kk * 32 + g * 8];
                short8 bk  = *(const short8*)&wq_d[(size_t)(128 + hh * 16 + lo) * 64 + kk * 32 + g * 8];
                short8 bv2 = *(const short8*)&wq_d[(size_t)(256 + hh * 16 + lo) * 64 + kk * 32 + g * 8];
#pragma unroll
                for (int mt = 0; mt < 2; ++mt) {
                    aq[mt] = __builtin_amdgcn_mfma_f32_16x16x32_bf16(af[mt][kk], bq,  aq[mt], 0, 0, 0);
                    ak[mt] = __builtin_amdgcn_mfma_f32_16x16x32_bf16(af[mt][kk], bk,  ak[mt], 0, 0, 0);
                    av[mt] = __builtin_amdgcn_mfma_f32_16x16x32_bf16(af[mt][kk], bv2, av[mt], 0, 0, 0);
                }
            }
            // store to wave-private LDS
#pragma unroll
            for (int mt = 0; mt < 2; ++mt)
#pragma unroll
                for (int rg = 0; rg < 4; ++rg) {
                    int tok = mt * 16 + g * 4 + rg;
                    qh[w * 32 + tok][lo] = __float2bfloat16(aq[mt][rg]);
                    kh[w * 32 + tok][lo] = __float2bfloat16(ak[mt][rg]);
                    vth[w][lo][tok]      = __float2bfloat16(av[mt][rg]);
                }
            // QK^T (K=32, upper 16 zero-padded)
            short8 aq0 = *(const short8*)&qh[w * 32 + lo][g * 8];
            short8 aq1 = *(const short8*)&qh[w * 32 + 16 + lo][g * 8];
            short8 bk0 = *(const short8*)&kh[w * 32 + lo][g * 8];
            short8 bk1 = *(const short8*)&kh[w * 32 + 16 + lo][g * 8];
            f32x4 S[2][2];
            S[0][0] = __builtin_amdgcn_mfma_f32_16x16x32_bf16(aq0, bk0, z4, 0, 0, 0);
            S[0][1] = __builtin_amdgcn_mfma_f32_16x16x32_bf16(aq0, bk1, z4, 0, 0, 0);
            S[1][0] = __builtin_amdgcn_mfma_f32_16x16x32_bf16(aq1, bk0, z4, 0, 0, 0);
            S[1][1] = __builtin_amdgcn_mfma_f32_16x16x32_bf16(aq1, bk1, z4, 0, 0, 0);
            // softmax per q-row (row on 16 lanes)
#pragma unroll
            for (int qt = 0; qt < 2; ++qt)
#pragma unroll
                for (int rg = 0; rg < 4; ++rg) {
                    float s0 = S[qt][0][rg] * 0.25f;
                    float s1 = S[qt][1][rg] * 0.25f;
                    float mx = fmaxf(s0, s1);
#pragma unroll
                    for (int msk = 1; msk < 16; msk <<= 1) mx = fmaxf(mx, __shfl_xor(mx, msk));
                    float e0 = __expf(s0 - mx), e1 = __expf(s1 - mx);
                    float sm = e0 + e1;
#pragma unroll
                    for (int msk = 1; msk < 16; msk <<= 1) sm += __shfl_xor(sm, msk);
                    float rs = 1.f / sm;
                    int q = qt * 16 + g * 4 + rg;
                    int key = (q >> 1) & 3;
                    int j0 = lo, j1 = 16 + lo;
                    Ps[w][q][((((j0 >> 3) ^ key) << 3) | (j0 & 7))] = __float2bfloat16(e0 * rs);
                    Ps[w][q][((((j1 >> 3) ^ key) << 3) | (j1 & 7))] = __float2bfloat16(e1 * rs);
                }
            // PV -> os (U cols hh*16..)
            short8 bv = *(const short8*)&vth[w][lo][g * 8];
#pragma unroll
            for (int qt = 0; qt < 2; ++qt) {
                int qrow = qt * 16 + lo;
                short8 ap = *(const short8*)&Ps[w][qrow][(g ^ ((qrow >> 1) & 3)) * 8];
                f32x4 ov = __builtin_amdgcn_mfma_f32_16x16x32_bf16(ap, bv, z4, 0, 0, 0);
#pragma unroll
                for (int rg = 0; rg < 4; ++rg)
                    U[w * 32 + qt * 16 + g * 4 + rg][hh * 16 + lo] = __float2bfloat16(ov[rg]);
            }
        }

        // ---- proj + residual: xs += os @ woT^T + bo ----
        {
            short8 ap2[2][4];
#pragma unroll
            for (int mt = 0; mt < 2; ++mt)
#pragma unroll
                for (int kk = 0; kk < 4; ++kk)
                    ap2[mt][kk] = *(const short8*)&U[w * 32 + mt * 16 + lo][kk * 32 + g * 8];
            f32x4 pacc[2][4];
#pragma unroll
            for (int mt = 0; mt < 2; ++mt)
#pragma unroll
                for (int nt = 0; nt < 4; ++nt) pacc[mt][nt] = z4;
#pragma unroll
            for (int kk = 0; kk < 4; ++kk)
#pragma unroll
                for (int nt = 0; nt < 4; ++nt) {
                    short8 b = *(const short8*)&wo_d[(size_t)(nt * 16 + lo) * 128 + kk * 32 + g * 8];
#pragma unroll
                    for (int mt = 0; mt < 2; ++mt)
                        pacc[mt][nt] = __builtin_amdgcn_mfma_f32_16x16x32_bf16(ap2[mt][kk], b, pacc[mt][nt], 0, 0, 0);
                }
#pragma unroll
            for (int mt = 0; mt < 2; ++mt)
#pragma unroll
                for (int nt = 0; nt < 4; ++nt)
#pragma unroll
                    for (int rg = 0; rg < 4; ++rg)
                        xs[w * 32 + mt * 16 + g * 4 + rg][nt * 16 + lo] += pacc[mt][nt][rg] + bo[d * 64 + nt * 16 + lo];
        }

        // ---- LN2 ----
        layernorm(ln2_g + d * 64, ln2_b + d * 64);

        // ---- ff1(geglu) + ff2, chunked (64 p-cols at a time) ----
        {
            short8 af2[2][2];
#pragma unroll
            for (int mt = 0; mt < 2; ++mt)
#pragma unroll
                for (int kk = 0; kk < 2; ++kk)
                    af2[mt][kk] = *(const short8*)&U[w * 32 + mt * 16 + lo][kk * 32 + g * 8];
            f32x4 acc2[2][4];
#pragma unroll
            for (int mt = 0; mt < 2; ++mt)
#pragma unroll
                for (int nt = 0; nt < 4; ++nt) acc2[mt][nt] = z4;

            for (int c4 = 0; c4 < 4; ++c4) {
                f32x4 aa[2][4], agg[2][4];
#pragma unroll
                for (int mt = 0; mt < 2; ++mt)
#pragma unroll
                    for (int nt = 0; nt < 4; ++nt) { aa[mt][nt] = z4; agg[mt][nt] = z4; }
#pragma unroll
                for (int kk = 0; kk < 2; ++kk)
#pragma unroll
                    for (int nt = 0; nt < 4; ++nt) {
                        short8 ba = *(const short8*)&w1_d[(size_t)(c4 * 64 + nt * 16 + lo) * 64 + kk * 32 + g * 8];
                        short8 bg = *(const short8*)&w1_d[(size_t)(256 + c4 * 64 + nt * 16 + lo) * 64 + kk * 32 + g * 8];
#pragma unroll
                        for (int mt = 0; mt < 2; ++mt) {
                            aa[mt][nt]  = __builtin_amdgcn_mfma_f32_16x16x32_bf16(af2[mt][kk], ba, aa[mt][nt], 0, 0, 0);
                            agg[mt][nt] = __builtin_amdgcn_mfma_f32_16x16x32_bf16(af2[mt][kk], bg, agg[mt][nt], 0, 0, 0);
                        }
                    }
                // geglu -> pg (U cols 0..63)
#pragma unroll
                for (int mt = 0; mt < 2; ++mt)
#pragma unroll
                    for (int nt = 0; nt < 4; ++nt)
#pragma unroll
                        for (int rg = 0; rg < 4; ++rg) {
                            int col = c4 * 64 + nt * 16 + lo;
                            float a  = aa[mt][nt][rg]  + bff1[d * 512 + col];
                            float gg = agg[mt][nt][rg] + bff1[d * 512 + 256 + col];
                            float gl = 0.5f * gg * (1.f + erff(gg * 0.70710678118654752f));
                            U[w * 32 + mt * 16 + g * 4 + rg][nt * 16 + lo] = __float2bfloat16(a * gl);
                        }
                // ff2 partial: acc2 += pg @ w2T^T (K-chunk c4)
                short8 apg[2][2];
#pragma unroll
                for (int mt = 0; mt < 2; ++mt)
#pragma unroll
                    for (int kk = 0; kk < 2; ++kk)
                        apg[mt][kk] = *(const short8*)&U[w * 32 + mt * 16 + lo][kk * 32 + g * 8];
#pragma unroll
                for (int kk = 0; kk < 2; ++kk)
#pragma unroll
                    for (int nt = 0; nt < 4; ++nt) {
                        short8 bb = *(const short8*)&w2_d[(size_t)(nt * 16 + lo) * 256 + c4 * 64 + kk * 32 + g * 8];
#pragma unroll
                        for (int mt = 0; mt < 2; ++mt)
                            acc2[mt][nt] = __builtin_amdgcn_mfma_f32_16x16x32_bf16(apg[mt][kk], bb, acc2[mt][nt], 0, 0, 0);
                    }
            }
            // residual
#pragma unroll
            for (int mt = 0; mt < 2; ++mt)
#pragma unroll
                for (int nt = 0; nt < 4; ++nt)
#pragma unroll
                    for (int rg = 0; rg < 4; ++rg)
                        xs[w * 32 + mt * 16 + g * 4 + rg][nt * 16 + lo] += acc2[mt][nt][rg] + bff2[d * 64 + nt * 16 + lo];
        }
    }

    // write Acat (bf16, cols 0..2047)
    {
        int r = w * 32 + (lane >> 1), half = lane & 1;
        int grow = r0 + r;
        int b = grow >> 5, i = grow & 31;
        size_t base = (size_t)b * KTOT + i * 64 + half * 32;
#pragma unroll
        for (int j = 0; j < 32; j += 2) {
            __hip_bfloat16 h0 = __float2bfloat16(xs[r][half * 32 + j]);
            __hip_bfloat16 h1 = __float2bfloat16(xs[r][half * 32 + j + 1]);
            unsigned u = ((unsigned)(*(unsigned short*)&h1) << 16) | (unsigned)(*(unsigned short*)&h0);
            *(unsigned*)&Acat[base + j] = u;
        }
    }
}

// ---------------------------------------------------------------------------
// BatchNorm1d (batch stats), one block per feature column.
// ---------------------------------------------------------------------------
__global__ __launch_bounds__(256) void k_bn(
    const float* __restrict__ x_cont, const float* __restrict__ bn_g, const float* __restrict__ bn_b,
    float* __restrict__ normed, __hip_bfloat16* __restrict__ Acat)
{
    const int c = blockIdx.x;
    const int tid = threadIdx.x;
    float sum = 0.f, sq = 0.f;
    for (int rr = tid; rr < B_; rr += 256) { float v = x_cont[rr * NCONT + c]; sum += v; sq += v * v; }
    __shared__ float ssum[256], ssq[256];
    ssum[tid] = sum; ssq[tid] = sq;
    __syncthreads();
    for (int st = 128; st > 0; st >>= 1) {
        if (tid < st) { ssum[tid] += ssum[tid + st]; ssq[tid] += ssq[tid + st]; }
        __syncthreads();
    }
    float mu  = ssum[0] * (1.f / B_);
    float var = ssq[0] * (1.f / B_) - mu * mu;
    float ri  = rsqrtf(var + 1e-5f);
    float gg = bn_g[c], bb = bn_b[c];
    for (int rr = tid; rr < B_; rr += 256) {
        float v = (x_cont[rr * NCONT + c] - mu) * ri * gg + bb;
        normed[rr * NCONT + c] = v;
        Acat[(size_t)rr * KTOT + CATF + c] = __float2bfloat16(v);
    }
}

// ---------------------------------------------------------------------------
// g0_w [2112,2048] fp32 -> WT [2048,2112] bf16 (k-contiguous)
// ---------------------------------------------------------------------------
__global__ __launch_bounds__(256) void k_transpose(
    const float* __restrict__ W, __hip_bfloat16* __restrict__ WT)
{
    __shared__ float tile[64][65];
    const int n0 = blockIdx.x * 64, k0 = blockIdx.y * 64;
    const int tid = threadIdx.x;
    for (int e = tid; e < 64 * 16; e += 256) {
        int rr = e >> 4, c4 = e & 15;
        float4 v = *(const float4*)&W[(size_t)(k0 + rr) * CATF + n0 + c4 * 4];
        tile[rr][c4 * 4 + 0] = v.x; tile[rr][c4 * 4 + 1] = v.y;
        tile[rr][c4 * 4 + 2] = v.z; tile[rr][c4 * 4 + 3] = v.w;
    }
    __syncthreads();
    for (int e = tid; e < 64 * 32; e += 256) {
        int n = e >> 5, kp = e & 31;
        __hip_bfloat16 h0 = __float2bfloat16(tile[kp * 2 + 0][n]);
        __hip_bfloat16 h1 = __float2bfloat16(tile[kp * 2 + 1][n]);
        unsigned u = ((unsigned)(*(unsigned short*)&h1) << 16) | (unsigned)(*(unsigned short*)&h0);
        *(unsigned*)&WT[(size_t)(n0 + n) * KTOT + k0 + kp * 2] = u;
    }
}

// ---------------------------------------------------------------------------
// G = relu(Acat[4096,2112] @ g0_w + g0_b), bf16 MFMA, 128x128 tiles
// ---------------------------------------------------------------------------
__global__ __launch_bounds__(256) void k_gemm_g0(
    const __hip_bfloat16* __restrict__ Acat, const __hip_bfloat16* __restrict__ WT,
    const float* __restrict__ g0_b, __hip_bfloat16* __restrict__ G)
{
    __shared__ unsigned short At[128][40];
    __shared__ unsigned short Bt[128][40];
    const int tid = threadIdx.x;
    const int m0 = blockIdx.y * 128, n0 = blockIdx.x * 128;
    const int w = tid >> 6, lane = tid & 63;
    const int wr = w >> 1, wc = w & 1;

    f32x4 acc[4][4];
#pragma unroll
    for (int mi = 0; mi < 4; ++mi)
#pragma unroll
        for (int ni = 0; ni < 4; ++ni) acc[mi][ni] = f32x4{0.f, 0.f, 0.f, 0.f};

    const int row_a = wr * 64 + (lane & 15);
    const int row_b = wc * 64 + (lane & 15);
    const int koff = (lane >> 4) * 8;

    for (int kt = 0; kt < KTOT / 32; ++kt) {
        const int k0 = kt * 32;
        for (int e = tid; e < 512; e += 256) {
            int rr = e >> 2, seg = e & 3;
            *(uint4*)&At[rr][seg * 8] = *(const uint4*)&Acat[(size_t)(m0 + rr) * KTOT + k0 + seg * 8];
        }
        for (int e = tid; e < 512; e += 256) {
            int rr = e >> 2, seg = e & 3;
            *(uint4*)&Bt[rr][seg * 8] = *(const uint4*)&WT[(size_t)(n0 + rr) * KTOT + k0 + seg * 8];
        }
        __syncthreads();
        short8 af[4], bfr[4];
#pragma unroll
        for (int mi = 0; mi < 4; ++mi) af[mi] = *(const short8*)&At[row_a + mi * 16][koff];
#pragma unroll
        for (int ni = 0; ni < 4; ++ni) bfr[ni] = *(const short8*)&Bt[row_b + ni * 16][koff];
#pragma unroll
        for (int mi = 0; mi < 4; ++mi)
#pragma unroll
            for (int ni = 0; ni < 4; ++ni)
                acc[mi][ni] = __builtin_amdgcn_mfma_f32_16x16x32_bf16(af[mi], bfr[ni], acc[mi][ni], 0, 0, 0);
        __syncthreads();
    }

#pragma unroll
    for (int mi = 0; mi < 4; ++mi)
#pragma unroll
        for (int ni = 0; ni < 4; ++ni)
#pragma unroll
            for (int reg = 0; reg < 4; ++reg) {
                int row = m0 + wr * 64 + mi * 16 + (lane >> 4) * 4 + reg;
                int col = n0 + wc * 64 + ni * 16 + (lane & 15);
                float v = acc[mi][ni][reg] + g0_b[col];
                G[(size_t)row * CATF + col] = __float2bfloat16(fmaxf(v, 0.f));
            }
}

// ---------------------------------------------------------------------------
// y1 = flat_categ @ y1_w + y1_b.  MFMA, M=4096 N=64 K=2048, 128-row blocks.
// ---------------------------------------------------------------------------
__global__ __launch_bounds__(256) void k_y1v2(
    const __hip_bfloat16* __restrict__ Acat, const __hip_bfloat16* __restrict__ y1T,
    const float* __restrict__ y1_b, float* __restrict__ y1)
{
    __shared__ __hip_bfloat16 At[128][136];
    __shared__ __hip_bfloat16 Bt[64][136];
    const int tid = threadIdx.x;
    const size_t m0 = (size_t)blockIdx.x * 128;
    const int w = tid >> 6, lane = tid & 63, lo = lane & 15, g = lane >> 4;
    f32x4 acc[2][4];
#pragma unroll
    for (int mt = 0; mt < 2; ++mt)
#pragma unroll
        for (int nt = 0; nt < 4; ++nt) acc[mt][nt] = f32x4{0.f, 0.f, 0.f, 0.f};
    for (int kt = 0; kt < 16; ++kt) {
        if (kt) __syncthreads();
#pragma unroll
        for (int t = 0; t < 8; ++t) {
            int e = tid + t * 256; int row = e >> 4, seg = e & 15;
            *(uint4*)&At[row][seg * 8] = *(const uint4*)&Acat[(m0 + row) * KTOT + kt * 128 + seg * 8];
        }
#pragma unroll
        for (int t = 0; t < 4; ++t) {
            int e = tid + t * 256; int row = e >> 4, seg = e & 15;
            *(uint4*)&Bt[row][seg * 8] = *(const uint4*)&y1T[(size_t)row * 2048 + kt * 128 + seg * 8];
        }
        __syncthreads();
#pragma unroll
        for (int kk = 0; kk < 4; ++kk) {
            short8 a[2], b[4];
#pragma unroll
            for (int mt = 0; mt < 2; ++mt) a[mt] = *(const short8*)&At[w * 32 + mt * 16 + lo][kk * 32 + g * 8];
#pragma unroll
            for (int nt = 0; nt < 4; ++nt) b[nt] = *(const short8*)&Bt[nt * 16 + lo][kk * 32 + g * 8];
#pragma unroll
            for (int mt = 0; mt < 2; ++mt)
#pragma unroll
                for (int nt = 0; nt < 4; ++nt)
                    acc[mt][nt] = __builtin_amdgcn_mfma_f32_16x16x32_bf16(a[mt], b[nt], acc[mt][nt], 0, 0, 0);
        }
    }
#pragma unroll
    for (int mt = 0; mt < 2; ++mt)
#pragma unroll
        for (int nt = 0; nt < 4; ++nt)
#pragma unroll
            for (int rg = 0; rg < 4; ++rg) {
                size_t row = m0 + w * 32 + mt * 16 + g * 4 + rg;
                int col = nt * 16 + lo;
                y1[row * 64 + col] = acc[mt][nt][rg] + y1_b[col];
            }
}

// ---------------------------------------------------------------------------
// H = G * (normed @ h0_w), in-place over G. MFMA, M=4096 N=2048 K=64.
// ---------------------------------------------------------------------------
__global__ __launch_bounds__(256) void k_H2(
    const __hip_bfloat16* __restrict__ Acat, const __hip_bfloat16* __restrict__ h0T,
    __hip_bfloat16* __restrict__ G)
{
    __shared__ __hip_bfloat16 At[128][72];
    const int tid = threadIdx.x;
    const int m0 = blockIdx.y * 128, n0 = blockIdx.x * 128;
    const int w = tid >> 6, lane = tid & 63, lo = lane & 15, g = lane >> 4;
    const int wr = w >> 1, wc = w & 1;
#pragma unroll
    for (int t = 0; t < 4; ++t) {
        int e = tid + t * 256; int row = e >> 3, seg = e & 7;
        *(uint4*)&At[row][seg * 8] = *(const uint4*)&Acat[(size_t)(m0 + row) * KTOT + CATF + seg * 8];
    }
    __syncthreads();
    f32x4 acc[4][4];
#pragma unroll
    for (int mt = 0; mt < 4; ++mt)
#pragma unroll
        for (int nt = 0; nt < 4; ++nt) acc[mt][nt] = f32x4{0.f, 0.f, 0.f, 0.f};
#pragma unroll
    for (int kk = 0; kk < 2; ++kk) {
        short8 a[4], b[4];
#pragma unroll
        for (int mt = 0; mt < 4; ++mt) a[mt] = *(const short8*)&At[wr * 64 + mt * 16 + lo][kk * 32 + g * 8];
#pragma unroll
        for (int nt = 0; nt < 4; ++nt)
            b[nt] = *(const short8*)&h0T[(size_t)(n0 + wc * 64 + nt * 16 + lo) * 64 + kk * 32 + g * 8];
#pragma unroll
        for (int mt = 0; mt < 4; ++mt)
#pragma unroll
            for (int nt = 0; nt < 4; ++nt)
                acc[mt][nt] = __builtin_amdgcn_mfma_f32_16x16x32_bf16(a[mt], b[nt], acc[mt][nt], 0, 0, 0);
    }
#pragma unroll
    for (int mt = 0; mt < 4; ++mt)
#pragma unroll
        for (int nt = 0; nt < 4; ++nt)
#pragma unroll
            for (int rg = 0; rg < 4; ++rg) {
                size_t row = (size_t)m0 + wr * 64 + mt * 16 + g * 4 + rg;
                int col = n0 + wc * 64 + nt * 16 + lo;
                size_t offo = row * CATF + col;
                G[offo] = __float2bfloat16(bf2f(G[offo]) * acc[mt][nt][rg]);
            }
}

// ---------------------------------------------------------------------------
// Final: norms, alpha, c0/c1 combine, fc dot, sigmoid. One block per row.
// ---------------------------------------------------------------------------
__global__ __launch_bounds__(256) void k_final(
    const __hip_bfloat16* __restrict__ Acat, const __hip_bfloat16* __restrict__ H,
    const float* __restrict__ normed, const float* __restrict__ y1,
    const float* __restrict__ g1_w, const float* __restrict__ g1_b, const float* __restrict__ h1_w,
    const float* __restrict__ fc_w, const float* __restrict__ fc_b,
    float* __restrict__ out)
{
    const int b = blockIdx.x;
    const int tid = threadIdx.x;
    const __hip_bfloat16* xrow = Acat + (size_t)b * KTOT;
    const __hip_bfloat16* hrow = H + (size_t)b * CATF;

    __shared__ float r1[256], r2[256];
    float sx = 0.f, sh = 0.f;
    for (int n = tid; n < CATF; n += 256) {
        float xv = bf2f(xrow[n]); sx += xv * xv;
        float hv = bf2f(hrow[n]); sh += hv * hv;
    }
    r1[tid] = sx; r2[tid] = sh;
    __syncthreads();
    for (int st = 128; st > 0; st >>= 1) {
        if (tid < st) { r1[tid] += r1[tid + st]; r2[tid] += r2[tid + st]; }
        __syncthreads();
    }
    float alpha0 = fminf(fmaxf(sqrtf(r1[0]) / (sqrtf(r2[0]) + 1e-12f) * 0.2f, 0.f), 1.f);
    __syncthreads();

    float pd = 0.f;
    for (int n = tid; n < CATF; n += 256) {
        float c0 = bf2f(xrow[n]) + alpha0 * bf2f(hrow[n]);
        pd += c0 * fc_w[n];
    }
    r1[tid] = pd;
    __syncthreads();
    for (int st = 128; st > 0; st >>= 1) {
        if (tid < st) r1[tid] += r1[tid + st];
        __syncthreads();
    }
    float dot0 = r1[0];

    __shared__ float ny[128];
    __shared__ float c1dot;
    if (tid < 64) ny[tid] = normed[b * NCONT + tid];
    else if (tid < 128) ny[tid] = y1[b * NCONT + tid - 64];
    __syncthreads();

    if (tid < 64) {
        const int j = tid;
        float g = g1_b[j];
        for (int k = 0; k < 128; ++k) g += ny[k] * g1_w[k * 64 + j];
        g = fmaxf(g, 0.f);
        float hv = 0.f;
        for (int k = 0; k < 64; ++k) hv += ny[64 + k] * h1_w[k * 64 + j];
        float H1 = g * hv;
        float nj = ny[j];
        float snx = nj * nj, snh = H1 * H1;
        for (int m = 1; m < 64; m <<= 1) { snx += __shfl_xor(snx, m, 64); snh += __shfl_xor(snh, m, 64); }
        float a1 = fminf(fmaxf(sqrtf(snx) / (sqrtf(snh) + 1e-12f) * 0.2f, 0.f), 1.f);
        float d1 = (nj + a1 * H1) * fc_w[CATF + j];
        for (int m = 1; m < 64; m <<= 1) d1 += __shfl_xor(d1, m, 64);
        if (tid == 0) c1dot = d1;
    }
    __syncthreads();
    if (tid == 0) {
        float logit = dot0 + c1dot + fc_b[0];
        out[b] = 1.f / (1.f + expf(-logit));
    }
}

// ---------------------------------------------------------------------------
extern "C" void kernel_launch(void* const* d_in, const int* in_sizes, int n_in,
                              void* d_out, int out_size, void* d_ws, size_t ws_size,
                              hipStream_t stream)
{
    const int*   x_categ = (const int*)d_in[0];
    const float* x_cont  = (const float*)d_in[1];
    const float* embed   = (const float*)d_in[2];
    const float* ln1_g   = (const float*)d_in[3];
    const float* ln1_b   = (const float*)d_in[4];
    const float* wqkv    = (const float*)d_in[5];
    const float* wo      = (const float*)d_in[6];
    const float* bo      = (const float*)d_in[7];
    const float* ln2_g   = (const float*)d_in[8];
    const float* ln2_b   = (const float*)d_in[9];
    const float* wff1    = (const float*)d_in[10];
    const float* bff1    = (const float*)d_in[11];
    const float* wff2    = (const float*)d_in[12];
    const float* bff2    = (const float*)d_in[13];
    const float* bn_g    = (const float*)d_in[14];
    const float* bn_b    = (const float*)d_in[15];
    const float* g0_w    = (const float*)d_in[16];
    const float* g0_b    = (const float*)d_in[17];
    const float* h0_w    = (const float*)d_in[18];
    const float* y1_w    = (const float*)d_in[19];
    const float* y1_b    = (const float*)d_in[20];
    const float* g1_w    = (const float*)d_in[21];
    const float* g1_b    = (const float*)d_in[22];
    const float* h1_w    = (const float*)d_in[23];
    const float* fc_w    = (const float*)d_in[24];
    const float* fc_b    = (const float*)d_in[25];

    // ---- workspace layout (no aliasing, ~46 MB) ----
    char* ws = (char*)d_ws;
    size_t off = 0;
    auto alloc = [&](size_t bytes) { void* pp = ws + off; off += (bytes + 255) & ~255ULL; return pp; };
    __hip_bfloat16* wqT  = (__hip_bfloat16*)alloc((size_t)DEPTH * 384 * 64 * 2);
    __hip_bfloat16* woT  = (__hip_bfloat16*)alloc((size_t)DEPTH * 64 * 128 * 2);
    __hip_bfloat16* w1T  = (__hip_bfloat16*)alloc((size_t)DEPTH * 512 * 64 * 2);
    __hip_bfloat16* w2T  = (__hip_bfloat16*)alloc((size_t)DEPTH * 64 * 256 * 2);
    __hip_bfloat16* h0T  = (__hip_bfloat16*)alloc((size_t)CATF * 64 * 2);
    __hip_bfloat16* y1T  = (__hip_bfloat16*)alloc((size_t)CATF * 64 * 2);
    __hip_bfloat16* Acat = (__hip_bfloat16*)alloc((size_t)B_ * KTOT * 2);
    __hip_bfloat16* WT   = (__hip_bfloat16*)alloc((size_t)CATF * KTOT * 2);
    __hip_bfloat16* G    = (__hip_bfloat16*)alloc((size_t)B_ * CATF * 2);
    float*          norm = (float*)alloc((size_t)B_ * NCONT * 4);
    float*          y1v  = (float*)alloc((size_t)B_ * NCONT * 4);

    // weight prep
    k_wT<<<576, 256, 0, stream>>>(wqkv, wqT, 64, 384);
    k_wT<<<192, 256, 0, stream>>>(wo,   woT, 128, 64);
    k_wT<<<768, 256, 0, stream>>>(wff1, w1T, 64, 512);
    k_wT<<<384, 256, 0, stream>>>(wff2, w2T, 256, 64);
    k_wT<<<512, 256, 0, stream>>>(h0_w, h0T, 64, 2048);
    k_wT<<<512, 256, 0, stream>>>(y1_w, y1T, 2048, 64);

    // transformer megakernel (emb + 6 layers + cast)
    k_former<<<NROW / 64, 128, 0, stream>>>(x_categ, embed, ln1_g, ln1_b, wqT, woT, bo,
                                            ln2_g, ln2_b, w1T, bff1, w2T, bff2, Acat);

    k_bn<<<NCONT, 256, 0, stream>>>(x_cont, bn_g, bn_b, norm, Acat);
    k_transpose<<<dim3(CATF / 64, KTOT / 64), 256, 0, stream>>>(g0_w, WT);
    k_gemm_g0<<<dim3(CATF / 128, B_ / 128), 256, 0, stream>>>(Acat, WT, g0_b, G);
    k_y1v2<<<B_ / 128, 256, 0, stream>>>(Acat, y1T, y1_b, y1v);
    k_H2<<<dim3(CATF / 128, B_ / 128), 256, 0, stream>>>(Acat, h0T, G);
    k_final<<<B_, 256, 0, stream>>>(Acat, G, norm, y1v, g1_w, g1_b, h1_w, fc_w, fc_b, (float*)d_out);
}

// Round 5
// 945.930 us; speedup vs baseline: 18.9750x; 1.1191x over previous
//
#include <hip/hip_runtime.h>
#include <hip/hip_bf16.h>

#define B_    4096
#define NC    32
#define DIM   64
#define INNER 128
#define HEADS 8
#define DH    16
#define DEPTH 6
#define NCONT 64
#define CATF  2048
#define KTOT  2112
#define NROW  (B_ * NC)          // 131072 token rows

typedef __attribute__((ext_vector_type(8))) short short8;
typedef __attribute__((ext_vector_type(4))) float f32x4;
typedef __attribute__((ext_vector_type(4))) unsigned short u16x4;

__device__ __forceinline__ float bf2f(__hip_bfloat16 h) { return __bfloat162float(h); }
__device__ __forceinline__ unsigned short f2bu(float f) {
    __hip_bfloat16 h = __float2bfloat16(f);
    return *(unsigned short*)&h;
}

// ---------------------------------------------------------------------------
// Generic weight transpose+cast: W [D][K][N] fp32 -> WT [D][N][K] bf16
// ---------------------------------------------------------------------------
__global__ __launch_bounds__(256) void k_wT(const float* __restrict__ W,
                                            __hip_bfloat16* __restrict__ WT,
                                            int K, int N)
{
    size_t idx = (size_t)blockIdx.x * 256 + threadIdx.x;
    int kn = K * N;
    int d = (int)(idx / kn), rem = (int)(idx % kn);
    int n = rem / K, k = rem % K;
    WT[idx] = __float2bfloat16(W[(size_t)d * kn + (size_t)k * N + n]);
}

// ---------------------------------------------------------------------------
// Transformer megakernel: emb + 6 layers + Acat cast. 2 samples/block,
// 128 threads (2 waves, wave w = sample w). Zero __syncthreads (wave-private
// LDS). Residual lives in REGISTERS (xacc, MFMA C layout). LDS = 31.5 KB
// -> 5 blocks/CU (10 waves/CU).
// ---------------------------------------------------------------------------
__global__ __launch_bounds__(128) void k_former(
    const int* __restrict__ x_categ, const float* __restrict__ embed,
    const float* __restrict__ ln1_g, const float* __restrict__ ln1_b,
    const __hip_bfloat16* __restrict__ wqT, const __hip_bfloat16* __restrict__ woT,
    const float* __restrict__ bo,
    const float* __restrict__ ln2_g, const float* __restrict__ ln2_b,
    const __hip_bfloat16* __restrict__ w1T, const float* __restrict__ bff1,
    const __hip_bfloat16* __restrict__ w2T, const float* __restrict__ bff2,
    __hip_bfloat16* __restrict__ Acat)
{
    __shared__ __align__(16) unsigned char Ub[64 * 136 * 2];   // 17.4 KB union
    auto U  = reinterpret_cast<__hip_bfloat16(*)[136]>(Ub);    // h / os / pg
    auto Uf = reinterpret_cast<float(*)[68]>(Ub);              // embed scratch
    __shared__ __hip_bfloat16 qh[64][40];        // per-head q, cols 16..31 zero
    __shared__ __hip_bfloat16 kh[64][40];        // per-head k
    __shared__ __hip_bfloat16 vth[2][16][40];    // per-head V^T [dh][token]
    __shared__ __hip_bfloat16 Ps[2][32][32];     // P, XOR-swizzled

    const int tid = threadIdx.x;
    const int w = tid >> 6, lane = tid & 63;
    const int lo = lane & 15, g = lane >> 4;
    const int r0 = blockIdx.x * 64;
    const f32x4 z4 = f32x4{0.f, 0.f, 0.f, 0.f};

    // residual stream in registers: (token = mt*16+g*4+rg, col = nt*16+lo)
    float xacc[2][4][4];

    // zero qh/kh cols 16..31 once (zero-padding for the K=32 QK^T MFMA)
    for (int i = lane; i < 32 * 16; i += 64) {
        int r = w * 32 + (i >> 4), c = 16 + (i & 15);
        qh[r][c] = __float2bfloat16(0.f);
        kh[r][c] = __float2bfloat16(0.f);
    }

    // embedding gather -> Uf (wave-local), then into xacc registers
    {
        int r = w * 32 + (lane >> 1), half = lane & 1;
        int grow = r0 + r;
        int tok = x_categ[grow] + 2 + 100 * (grow & 31);
        const float4* src = (const float4*)(embed + (size_t)tok * 64 + half * 32);
#pragma unroll
        for (int q4 = 0; q4 < 8; ++q4) {
            float4 v = src[q4];
            Uf[r][half * 32 + q4 * 4 + 0] = v.x; Uf[r][half * 32 + q4 * 4 + 1] = v.y;
            Uf[r][half * 32 + q4 * 4 + 2] = v.z; Uf[r][half * 32 + q4 * 4 + 3] = v.w;
        }
    }
#pragma unroll
    for (int mt = 0; mt < 2; ++mt)
#pragma unroll
        for (int nt = 0; nt < 4; ++nt)
#pragma unroll
            for (int rg = 0; rg < 4; ++rg)
                xacc[mt][nt][rg] = Uf[w * 32 + mt * 16 + g * 4 + rg][nt * 16 + lo];

    // LayerNorm: xacc regs -> U (bf16)
    auto layernorm = [&](const float* gam, const float* bet) {
        float gv[4], bv_[4];
#pragma unroll
        for (int nt = 0; nt < 4; ++nt) { gv[nt] = gam[nt * 16 + lo]; bv_[nt] = bet[nt * 16 + lo]; }
#pragma unroll
        for (int mt = 0; mt < 2; ++mt)
#pragma unroll
            for (int rg = 0; rg < 4; ++rg) {
                float s = xacc[mt][0][rg] + xacc[mt][1][rg] + xacc[mt][2][rg] + xacc[mt][3][rg];
                float q = xacc[mt][0][rg] * xacc[mt][0][rg] + xacc[mt][1][rg] * xacc[mt][1][rg]
                        + xacc[mt][2][rg] * xacc[mt][2][rg] + xacc[mt][3][rg] * xacc[mt][3][rg];
#pragma unroll
                for (int m = 1; m < 16; m <<= 1) { s += __shfl_xor(s, m); q += __shfl_xor(q, m); }
                float mu = s * (1.f / 64.f);
                float var = q * (1.f / 64.f) - mu * mu;
                float ri = rsqrtf(var + 1e-5f);
                int token = w * 32 + mt * 16 + g * 4 + rg;
#pragma unroll
                for (int nt = 0; nt < 4; ++nt)
                    U[token][nt * 16 + lo] = __float2bfloat16((xacc[mt][nt][rg] - mu) * ri * gv[nt] + bv_[nt]);
            }
    };

#pragma unroll 1
    for (int d = 0; d < DEPTH; ++d) {
        const __hip_bfloat16* wq_d = wqT + (size_t)d * 384 * 64;
        const __hip_bfloat16* wo_d = woT + (size_t)d * 64 * 128;
        const __hip_bfloat16* w1_d = w1T + (size_t)d * 512 * 64;
        const __hip_bfloat16* w2_d = w2T + (size_t)d * 64 * 256;

        // ---- LN1 ----
        layernorm(ln1_g + d * 64, ln1_b + d * 64);

        // A-frags of h (persist across heads)
        short8 af[2][2];
#pragma unroll
        for (int mt = 0; mt < 2; ++mt)
#pragma unroll
            for (int kk = 0; kk < 2; ++kk)
                af[mt][kk] = *(const short8*)&U[w * 32 + mt * 16 + lo][kk * 32 + g * 8];

        // ---- attention, per head ----
        for (int hh = 0; hh < HEADS; ++hh) {
            // qkv for this head (N=16 per part)
            f32x4 aq[2] = {z4, z4}, ak[2] = {z4, z4}, av[2] = {z4, z4};
#pragma unroll
            for (int kk = 0; kk < 2; ++kk) {
                short8 bq  = *(const short8*)&wq_d[(size_t)(hh * 16 + lo) * 64 + kk * 32 + g * 8];
                short8 bk  = *(const short8*)&wq_d[(size_t)(128 + hh * 16 + lo) * 64 + kk * 32 + g * 8];
                short8 bv2 = *(const short8*)&wq_d[(size_t)(256 + hh * 16 + lo) * 64 + kk * 32 + g * 8];
#pragma unroll
                for (int mt = 0; mt < 2; ++mt) {
                    aq[mt] = __builtin_amdgcn_mfma_f32_16x16x32_bf16(af[mt][kk], bq,  aq[mt], 0, 0, 0);
                    ak[mt] = __builtin_amdgcn_mfma_f32_16x16x32_bf16(af[mt][kk], bk,  ak[mt], 0, 0, 0);
                    av[mt] = __builtin_amdgcn_mfma_f32_16x16x32_bf16(af[mt][kk], bv2, av[mt], 0, 0, 0);
                }
            }
            // q/k scalar stores; V^T packed b64 stores (4 tokens contiguous)
#pragma unroll
            for (int mt = 0; mt < 2; ++mt) {
#pragma unroll
                for (int rg = 0; rg < 4; ++rg) {
                    int tok = mt * 16 + g * 4 + rg;
                    qh[w * 32 + tok][lo] = __float2bfloat16(aq[mt][rg]);
                    kh[w * 32 + tok][lo] = __float2bfloat16(ak[mt][rg]);
                }
                u16x4 vv;
                vv.x = f2bu(av[mt][0]); vv.y = f2bu(av[mt][1]);
                vv.z = f2bu(av[mt][2]); vv.w = f2bu(av[mt][3]);
                *(u16x4*)&vth[w][lo][mt * 16 + g * 4] = vv;
            }
            // QK^T (K=32, upper 16 zero-padded)
            short8 aq0 = *(const short8*)&qh[w * 32 + lo][g * 8];
            short8 aq1 = *(const short8*)&qh[w * 32 + 16 + lo][g * 8];
            short8 bk0 = *(const short8*)&kh[w * 32 + lo][g * 8];
            short8 bk1 = *(const short8*)&kh[w * 32 + 16 + lo][g * 8];
            f32x4 S[2][2];
            S[0][0] = __builtin_amdgcn_mfma_f32_16x16x32_bf16(aq0, bk0, z4, 0, 0, 0);
            S[0][1] = __builtin_amdgcn_mfma_f32_16x16x32_bf16(aq0, bk1, z4, 0, 0, 0);
            S[1][0] = __builtin_amdgcn_mfma_f32_16x16x32_bf16(aq1, bk0, z4, 0, 0, 0);
            S[1][1] = __builtin_amdgcn_mfma_f32_16x16x32_bf16(aq1, bk1, z4, 0, 0, 0);
            // softmax per q-row (row on 16 lanes)
#pragma unroll
            for (int qt = 0; qt < 2; ++qt)
#pragma unroll
                for (int rg = 0; rg < 4; ++rg) {
                    float s0 = S[qt][0][rg] * 0.25f;
                    float s1 = S[qt][1][rg] * 0.25f;
                    float mx = fmaxf(s0, s1);
#pragma unroll
                    for (int msk = 1; msk < 16; msk <<= 1) mx = fmaxf(mx, __shfl_xor(mx, msk));
                    float e0 = __expf(s0 - mx), e1 = __expf(s1 - mx);
                    float sm = e0 + e1;
#pragma unroll
                    for (int msk = 1; msk < 16; msk <<= 1) sm += __shfl_xor(sm, msk);
                    float rs = 1.f / sm;
                    int q = qt * 16 + g * 4 + rg;
                    int key = (q >> 1) & 3;
                    int j0 = lo, j1 = 16 + lo;
                    Ps[w][q][((((j0 >> 3) ^ key) << 3) | (j0 & 7))] = __float2bfloat16(e0 * rs);
                    Ps[w][q][((((j1 >> 3) ^ key) << 3) | (j1 & 7))] = __float2bfloat16(e1 * rs);
                }
            // PV -> os (U cols hh*16..)
            short8 bv = *(const short8*)&vth[w][lo][g * 8];
#pragma unroll
            for (int qt = 0; qt < 2; ++qt) {
                int qrow = qt * 16 + lo;
                short8 ap = *(const short8*)&Ps[w][qrow][(g ^ ((qrow >> 1) & 3)) * 8];
                f32x4 ov = __builtin_amdgcn_mfma_f32_16x16x32_bf16(ap, bv, z4, 0, 0, 0);
#pragma unroll
                for (int rg = 0; rg < 4; ++rg)
                    U[w * 32 + qt * 16 + g * 4 + rg][hh * 16 + lo] = __float2bfloat16(ov[rg]);
            }
        }

        // ---- proj + residual: xacc += os @ woT^T + bo ----
        {
            short8 ap2[2][4];
#pragma unroll
            for (int mt = 0; mt < 2; ++mt)
#pragma unroll
                for (int kk = 0; kk < 4; ++kk)
                    ap2[mt][kk] = *(const short8*)&U[w * 32 + mt * 16 + lo][kk * 32 + g * 8];
            f32x4 pacc[2][4];
#pragma unroll
            for (int mt = 0; mt < 2; ++mt)
#pragma unroll
                for (int nt = 0; nt < 4; ++nt) pacc[mt][nt] = z4;
#pragma unroll
            for (int kk = 0; kk < 4; ++kk)
#pragma unroll
                for (int nt = 0; nt < 4; ++nt) {
                    short8 b = *(const short8*)&wo_d[(size_t)(nt * 16 + lo) * 128 + kk * 32 + g * 8];
#pragma unroll
                    for (int mt = 0; mt < 2; ++mt)
                        pacc[mt][nt] = __builtin_amdgcn_mfma_f32_16x16x32_bf16(ap2[mt][kk], b, pacc[mt][nt], 0, 0, 0);
                }
            float bov[4];
#pragma unroll
            for (int nt = 0; nt < 4; ++nt) bov[nt] = bo[d * 64 + nt * 16 + lo];
#pragma unroll
            for (int mt = 0; mt < 2; ++mt)
#pragma unroll
                for (int nt = 0; nt < 4; ++nt)
#pragma unroll
                    for (int rg = 0; rg < 4; ++rg)
                        xacc[mt][nt][rg] += pacc[mt][nt][rg] + bov[nt];
        }

        // ---- LN2 ----
        layernorm(ln2_g + d * 64, ln2_b + d * 64);

        // ---- ff1(geglu) + ff2, chunked (64 p-cols at a time) ----
        {
            short8 af2[2][2];
#pragma unroll
            for (int mt = 0; mt < 2; ++mt)
#pragma unroll
                for (int kk = 0; kk < 2; ++kk)
                    af2[mt][kk] = *(const short8*)&U[w * 32 + mt * 16 + lo][kk * 32 + g * 8];
            f32x4 acc2[2][4];
#pragma unroll
            for (int mt = 0; mt < 2; ++mt)
#pragma unroll
                for (int nt = 0; nt < 4; ++nt) acc2[mt][nt] = z4;

            for (int c4 = 0; c4 < 4; ++c4) {
                // geglu in two nt-halves (keeps aa/agg at [2][2] for VGPR)
#pragma unroll
                for (int nh = 0; nh < 2; ++nh) {
                    f32x4 aa[2][2], agg[2][2];
#pragma unroll
                    for (int mt = 0; mt < 2; ++mt)
#pragma unroll
                        for (int nj = 0; nj < 2; ++nj) { aa[mt][nj] = z4; agg[mt][nj] = z4; }
#pragma unroll
                    for (int kk = 0; kk < 2; ++kk)
#pragma unroll
                        for (int nj = 0; nj < 2; ++nj) {
                            int nt = nh * 2 + nj;
                            short8 ba = *(const short8*)&w1_d[(size_t)(c4 * 64 + nt * 16 + lo) * 64 + kk * 32 + g * 8];
                            short8 bg = *(const short8*)&w1_d[(size_t)(256 + c4 * 64 + nt * 16 + lo) * 64 + kk * 32 + g * 8];
#pragma unroll
                            for (int mt = 0; mt < 2; ++mt) {
                                aa[mt][nj]  = __builtin_amdgcn_mfma_f32_16x16x32_bf16(af2[mt][kk], ba, aa[mt][nj], 0, 0, 0);
                                agg[mt][nj] = __builtin_amdgcn_mfma_f32_16x16x32_bf16(af2[mt][kk], bg, agg[mt][nj], 0, 0, 0);
                            }
                        }
#pragma unroll
                    for (int mt = 0; mt < 2; ++mt)
#pragma unroll
                        for (int nj = 0; nj < 2; ++nj)
#pragma unroll
                            for (int rg = 0; rg < 4; ++rg) {
                                int nt = nh * 2 + nj;
                                int col = c4 * 64 + nt * 16 + lo;
                                float a  = aa[mt][nj][rg]  + bff1[d * 512 + col];
                                float gg = agg[mt][nj][rg] + bff1[d * 512 + 256 + col];
                                float gl = 0.5f * gg * (1.f + erff(gg * 0.70710678118654752f));
                                U[w * 32 + mt * 16 + g * 4 + rg][nt * 16 + lo] = __float2bfloat16(a * gl);
                            }
                }
                // ff2 partial: acc2 += pg @ w2T^T (K-chunk c4)
                short8 apg[2][2];
#pragma unroll
                for (int mt = 0; mt < 2; ++mt)
#pragma unroll
                    for (int kk = 0; kk < 2; ++kk)
                        apg[mt][kk] = *(const short8*)&U[w * 32 + mt * 16 + lo][kk * 32 + g * 8];
#pragma unroll
                for (int kk = 0; kk < 2; ++kk)
#pragma unroll
                    for (int nt = 0; nt < 4; ++nt) {
                        short8 bb = *(const short8*)&w2_d[(size_t)(nt * 16 + lo) * 256 + c4 * 64 + kk * 32 + g * 8];
#pragma unroll
                        for (int mt = 0; mt < 2; ++mt)
                            acc2[mt][nt] = __builtin_amdgcn_mfma_f32_16x16x32_bf16(apg[mt][kk], bb, acc2[mt][nt], 0, 0, 0);
                    }
            }
            // residual
            float b2v[4];
#pragma unroll
            for (int nt = 0; nt < 4; ++nt) b2v[nt] = bff2[d * 64 + nt * 16 + lo];
#pragma unroll
            for (int mt = 0; mt < 2; ++mt)
#pragma unroll
                for (int nt = 0; nt < 4; ++nt)
#pragma unroll
                    for (int rg = 0; rg < 4; ++rg)
                        xacc[mt][nt][rg] += acc2[mt][nt][rg] + b2v[nt];
        }
    }

    // write Acat (bf16, cols 0..2047) straight from registers
    {
        size_t base = (size_t)(blockIdx.x * 2 + w) * KTOT;
#pragma unroll
        for (int mt = 0; mt < 2; ++mt)
#pragma unroll
            for (int rg = 0; rg < 4; ++rg) {
                int token = mt * 16 + g * 4 + rg;
#pragma unroll
                for (int nt = 0; nt < 4; ++nt)
                    Acat[base + token * 64 + nt * 16 + lo] = __float2bfloat16(xacc[mt][nt][rg]);
            }
    }
}

// ---------------------------------------------------------------------------
// BatchNorm1d (batch stats), one block per feature column.
// ---------------------------------------------------------------------------
__global__ __launch_bounds__(256) void k_bn(
    const float* __restrict__ x_cont, const float* __restrict__ bn_g, const float* __restrict__ bn_b,
    float* __restrict__ normed, __hip_bfloat16* __restrict__ Acat)
{
    const int c = blockIdx.x;
    const int tid = threadIdx.x;
    float sum = 0.f, sq = 0.f;
    for (int rr = tid; rr < B_; rr += 256) { float v = x_cont[rr * NCONT + c]; sum += v; sq += v * v; }
    __shared__ float ssum[256], ssq[256];
    ssum[tid] = sum; ssq[tid] = sq;
    __syncthreads();
    for (int st = 128; st > 0; st >>= 1) {
        if (tid < st) { ssum[tid] += ssum[tid + st]; ssq[tid] += ssq[tid + st]; }
        __syncthreads();
    }
    float mu  = ssum[0] * (1.f / B_);
    float var = ssq[0] * (1.f / B_) - mu * mu;
    float ri  = rsqrtf(var + 1e-5f);
    float gg = bn_g[c], bb = bn_b[c];
    for (int rr = tid; rr < B_; rr += 256) {
        float v = (x_cont[rr * NCONT + c] - mu) * ri * gg + bb;
        normed[rr * NCONT + c] = v;
        Acat[(size_t)rr * KTOT + CATF + c] = __float2bfloat16(v);
    }
}

// ---------------------------------------------------------------------------
// g0_w [2112,2048] fp32 -> WT [2048,2112] bf16 (k-contiguous)
// ---------------------------------------------------------------------------
__global__ __launch_bounds__(256) void k_transpose(
    const float* __restrict__ W, __hip_bfloat16* __restrict__ WT)
{
    __shared__ float tile[64][65];
    const int n0 = blockIdx.x * 64, k0 = blockIdx.y * 64;
    const int tid = threadIdx.x;
    for (int e = tid; e < 64 * 16; e += 256) {
        int rr = e >> 4, c4 = e & 15;
        float4 v = *(const float4*)&W[(size_t)(k0 + rr) * CATF + n0 + c4 * 4];
        tile[rr][c4 * 4 + 0] = v.x; tile[rr][c4 * 4 + 1] = v.y;
        tile[rr][c4 * 4 + 2] = v.z; tile[rr][c4 * 4 + 3] = v.w;
    }
    __syncthreads();
    for (int e = tid; e < 64 * 32; e += 256) {
        int n = e >> 5, kp = e & 31;
        __hip_bfloat16 h0 = __float2bfloat16(tile[kp * 2 + 0][n]);
        __hip_bfloat16 h1 = __float2bfloat16(tile[kp * 2 + 1][n]);
        unsigned u = ((unsigned)(*(unsigned short*)&h1) << 16) | (unsigned)(*(unsigned short*)&h0);
        *(unsigned*)&WT[(size_t)(n0 + n) * KTOT + k0 + kp * 2] = u;
    }
}

// ---------------------------------------------------------------------------
// G = relu(Acat[4096,2112] @ g0_w + g0_b), bf16 MFMA, 128x128 tiles, BK=64
// ---------------------------------------------------------------------------
__global__ __launch_bounds__(256) void k_gemm_g0(
    const __hip_bfloat16* __restrict__ Acat, const __hip_bfloat16* __restrict__ WT,
    const float* __restrict__ g0_b, __hip_bfloat16* __restrict__ G)
{
    __shared__ __hip_bfloat16 At[128][72];
    __shared__ __hip_bfloat16 Bt[128][72];
    const int tid = threadIdx.x;
    const int m0 = blockIdx.y * 128, n0 = blockIdx.x * 128;
    const int w = tid >> 6, lane = tid & 63, g = lane >> 4;
    const int wr = w >> 1, wc = w & 1;

    f32x4 acc[4][4];
#pragma unroll
    for (int mi = 0; mi < 4; ++mi)
#pragma unroll
        for (int ni = 0; ni < 4; ++ni) acc[mi][ni] = f32x4{0.f, 0.f, 0.f, 0.f};

    const int row_a = wr * 64 + (lane & 15);
    const int row_b = wc * 64 + (lane & 15);

    for (int kt = 0; kt < KTOT / 64; ++kt) {
        const int k0 = kt * 64;
#pragma unroll
        for (int t = 0; t < 4; ++t) {
            int e = tid + t * 256; int rr = e >> 3, seg = e & 7;
            *(uint4*)&At[rr][seg * 8] = *(const uint4*)&Acat[(size_t)(m0 + rr) * KTOT + k0 + seg * 8];
        }
#pragma unroll
        for (int t = 0; t < 4; ++t) {
            int e = tid + t * 256; int rr = e >> 3, seg = e & 7;
            *(uint4*)&Bt[rr][seg * 8] = *(const uint4*)&WT[(size_t)(n0 + rr) * KTOT + k0 + seg * 8];
        }
        __syncthreads();
        short8 af[4][2], bfr[4][2];
#pragma unroll
        for (int mi = 0; mi < 4; ++mi)
#pragma unroll
            for (int kk = 0; kk < 2; ++kk)
                af[mi][kk] = *(const short8*)&At[row_a + mi * 16][kk * 32 + g * 8];
#pragma unroll
        for (int ni = 0; ni < 4; ++ni)
#pragma unroll
            for (int kk = 0; kk < 2; ++kk)
                bfr[ni][kk] = *(const short8*)&Bt[row_b + ni * 16][kk * 32 + g * 8];
#pragma unroll
        for (int kk = 0; kk < 2; ++kk)
#pragma unroll
            for (int mi = 0; mi < 4; ++mi)
#pragma unroll
                for (int ni = 0; ni < 4; ++ni)
                    acc[mi][ni] = __builtin_amdgcn_mfma_f32_16x16x32_bf16(af[mi][kk], bfr[ni][kk], acc[mi][ni], 0, 0, 0);
        __syncthreads();
    }

#pragma unroll
    for (int mi = 0; mi < 4; ++mi)
#pragma unroll
        for (int ni = 0; ni < 4; ++ni)
#pragma unroll
            for (int reg = 0; reg < 4; ++reg) {
                int row = m0 + wr * 64 + mi * 16 + (lane >> 4) * 4 + reg;
                int col = n0 + wc * 64 + ni * 16 + (lane & 15);
                float v = acc[mi][ni][reg] + g0_b[col];
                G[(size_t)row * CATF + col] = __float2bfloat16(fmaxf(v, 0.f));
            }
}

// ---------------------------------------------------------------------------
// y1 = flat_categ @ y1_w + y1_b.  MFMA, M=4096 N=64 K=2048, 128-row blocks.
// ---------------------------------------------------------------------------
__global__ __launch_bounds__(256) void k_y1v2(
    const __hip_bfloat16* __restrict__ Acat, const __hip_bfloat16* __restrict__ y1T,
    const float* __restrict__ y1_b, float* __restrict__ y1)
{
    __shared__ __hip_bfloat16 At[128][136];
    __shared__ __hip_bfloat16 Bt[64][136];
    const int tid = threadIdx.x;
    const size_t m0 = (size_t)blockIdx.x * 128;
    const int w = tid >> 6, lane = tid & 63, lo = lane & 15, g = lane >> 4;
    f32x4 acc[2][4];
#pragma unroll
    for (int mt = 0; mt < 2; ++mt)
#pragma unroll
        for (int nt = 0; nt < 4; ++nt) acc[mt][nt] = f32x4{0.f, 0.f, 0.f, 0.f};
    for (int kt = 0; kt < 16; ++kt) {
        if (kt) __syncthreads();
#pragma unroll
        for (int t = 0; t < 8; ++t) {
            int e = tid + t * 256; int row = e >> 4, seg = e & 15;
            *(uint4*)&At[row][seg * 8] = *(const uint4*)&Acat[(m0 + row) * KTOT + kt * 128 + seg * 8];
        }
#pragma unroll
        for (int t = 0; t < 4; ++t) {
            int e = tid + t * 256; int row = e >> 4, seg = e & 15;
            *(uint4*)&Bt[row][seg * 8] = *(const uint4*)&y1T[(size_t)row * 2048 + kt * 128 + seg * 8];
        }
        __syncthreads();
#pragma unroll
        for (int kk = 0; kk < 4; ++kk) {
            short8 a[2], b[4];
#pragma unroll
            for (int mt = 0; mt < 2; ++mt) a[mt] = *(const short8*)&At[w * 32 + mt * 16 + lo][kk * 32 + g * 8];
#pragma unroll
            for (int nt = 0; nt < 4; ++nt) b[nt] = *(const short8*)&Bt[nt * 16 + lo][kk * 32 + g * 8];
#pragma unroll
            for (int mt = 0; mt < 2; ++mt)
#pragma unroll
                for (int nt = 0; nt < 4; ++nt)
                    acc[mt][nt] = __builtin_amdgcn_mfma_f32_16x16x32_bf16(a[mt], b[nt], acc[mt][nt], 0, 0, 0);
        }
    }
#pragma unroll
    for (int mt = 0; mt < 2; ++mt)
#pragma unroll
        for (int nt = 0; nt < 4; ++nt)
#pragma unroll
            for (int rg = 0; rg < 4; ++rg) {
                size_t row = m0 + w * 32 + mt * 16 + g * 4 + rg;
                int col = nt * 16 + lo;
                y1[row * 64 + col] = acc[mt][nt][rg] + y1_b[col];
            }
}

// ---------------------------------------------------------------------------
// H = G * (normed @ h0_w), in-place over G. MFMA, M=4096 N=2048 K=64.
// ---------------------------------------------------------------------------
__global__ __launch_bounds__(256) void k_H2(
    const __hip_bfloat16* __restrict__ Acat, const __hip_bfloat16* __restrict__ h0T,
    __hip_bfloat16* __restrict__ G)
{
    __shared__ __hip_bfloat16 At[128][72];
    const int tid = threadIdx.x;
    const int m0 = blockIdx.y * 128, n0 = blockIdx.x * 128;
    const int w = tid >> 6, lane = tid & 63, lo = lane & 15, g = lane >> 4;
    const int wr = w >> 1, wc = w & 1;
#pragma unroll
    for (int t = 0; t < 4; ++t) {
        int e = tid + t * 256; int row = e >> 3, seg = e & 7;
        *(uint4*)&At[row][seg * 8] = *(const uint4*)&Acat[(size_t)(m0 + row) * KTOT + CATF + seg * 8];
    }
    __syncthreads();
    f32x4 acc[4][4];
#pragma unroll
    for (int mt = 0; mt < 4; ++mt)
#pragma unroll
        for (int nt = 0; nt < 4; ++nt) acc[mt][nt] = f32x4{0.f, 0.f, 0.f, 0.f};
#pragma unroll
    for (int kk = 0; kk < 2; ++kk) {
        short8 a[4], b[4];
#pragma unroll
        for (int mt = 0; mt < 4; ++mt) a[mt] = *(const short8*)&At[wr * 64 + mt * 16 + lo][kk * 32 + g * 8];
#pragma unroll
        for (int nt = 0; nt < 4; ++nt)
            b[nt] = *(const short8*)&h0T[(size_t)(n0 + wc * 64 + nt * 16 + lo) * 64 + kk * 32 + g * 8];
#pragma unroll
        for (int mt = 0; mt < 4; ++mt)
#pragma unroll
            for (int nt = 0; nt < 4; ++nt)
                acc[mt][nt] = __builtin_amdgcn_mfma_f32_16x16x32_bf16(a[mt], b[nt], acc[mt][nt], 0, 0, 0);
    }
#pragma unroll
    for (int mt = 0; mt < 4; ++mt)
#pragma unroll
        for (int nt = 0; nt < 4; ++nt)
#pragma unroll
            for (int rg = 0; rg < 4; ++rg) {
                size_t row = (size_t)m0 + wr * 64 + mt * 16 + g * 4 + rg;
                int col = n0 + wc * 64 + nt * 16 + lo;
                size_t offo = row * CATF + col;
                G[offo] = __float2bfloat16(bf2f(G[offo]) * acc[mt][nt][rg]);
            }
}

// ---------------------------------------------------------------------------
// Final: norms, alpha, c0/c1 combine, fc dot, sigmoid. One block per row.
// ---------------------------------------------------------------------------
__global__ __launch_bounds__(256) void k_final(
    const __hip_bfloat16* __restrict__ Acat, const __hip_bfloat16* __restrict__ H,
    const float* __restrict__ normed, const float* __restrict__ y1,
    const float* __restrict__ g1_w, const float* __restrict__ g1_b, const float* __restrict__ h1_w,
    const float* __restrict__ fc_w, const float* __restrict__ fc_b,
    float* __restrict__ out)
{
    const int b = blockIdx.x;
    const int tid = threadIdx.x;
    const __hip_bfloat16* xrow = Acat + (size_t)b * KTOT;
    const __hip_bfloat16* hrow = H + (size_t)b * CATF;

    __shared__ float r1[256], r2[256];
    float sx = 0.f, sh = 0.f;
    for (int n = tid; n < CATF; n += 256) {
        float xv = bf2f(xrow[n]); sx += xv * xv;
        float hv = bf2f(hrow[n]); sh += hv * hv;
    }
    r1[tid] = sx; r2[tid] = sh;
    __syncthreads();
    for (int st = 128; st > 0; st >>= 1) {
        if (tid < st) { r1[tid] += r1[tid + st]; r2[tid] += r2[tid + st]; }
        __syncthreads();
    }
    float alpha0 = fminf(fmaxf(sqrtf(r1[0]) / (sqrtf(r2[0]) + 1e-12f) * 0.2f, 0.f), 1.f);
    __syncthreads();

    float pd = 0.f;
    for (int n = tid; n < CATF; n += 256) {
        float c0 = bf2f(xrow[n]) + alpha0 * bf2f(hrow[n]);
        pd += c0 * fc_w[n];
    }
    r1[tid] = pd;
    __syncthreads();
    for (int st = 128; st > 0; st >>= 1) {
        if (tid < st) r1[tid] += r1[tid + st];
        __syncthreads();
    }
    float dot0 = r1[0];

    __shared__ float ny[128];
    __shared__ float c1dot;
    if (tid < 64) ny[tid] = normed[b * NCONT + tid];
    else if (tid < 128) ny[tid] = y1[b * NCONT + tid - 64];
    __syncthreads();

    if (tid < 64) {
        const int j = tid;
        float g = g1_b[j];
        for (int k = 0; k < 128; ++k) g += ny[k] * g1_w[k * 64 + j];
        g = fmaxf(g, 0.f);
        float hv = 0.f;
        for (int k = 0; k < 64; ++k) hv += ny[64 + k] * h1_w[k * 64 + j];
        float H1 = g * hv;
        float nj = ny[j];
        float snx = nj * nj, snh = H1 * H1;
        for (int m = 1; m < 64; m <<= 1) { snx += __shfl_xor(snx, m, 64); snh += __shfl_xor(snh, m, 64); }
        float a1 = fminf(fmaxf(sqrtf(snx) / (sqrtf(snh) + 1e-12f) * 0.2f, 0.f), 1.f);
        float d1 = (nj + a1 * H1) * fc_w[CATF + j];
        for (int m = 1; m < 64; m <<= 1) d1 += __shfl_xor(d1, m, 64);
        if (tid == 0) c1dot = d1;
    }
    __syncthreads();
    if (tid == 0) {
        float logit = dot0 + c1dot + fc_b[0];
        out[b] = 1.f / (1.f + expf(-logit));
    }
}

// ---------------------------------------------------------------------------
extern "C" void kernel_launch(void* const* d_in, const int* in_sizes, int n_in,
                              void* d_out, int out_size, void* d_ws, size_t ws_size,
                              hipStream_t stream)
{
    const int*   x_categ = (const int*)d_in[0];
    const float* x_cont  = (const float*)d_in[1];
    const float* embed   = (const float*)d_in[2];
    const float* ln1_g   = (const float*)d_in[3];
    const float* ln1_b   = (const float*)d_in[4];
    const float* wqkv    = (const float*)d_in[5];
    const float* wo      = (const float*)d_in[6];
    const float* bo      = (const float*)d_in[7];
    const float* ln2_g   = (const float*)d_in[8];
    const float* ln2_b   = (const float*)d_in[9];
    const float* wff1    = (const float*)d_in[10];
    const float* bff1    = (const float*)d_in[11];
    const float* wff2    = (const float*)d_in[12];
    const float* bff2    = (const float*)d_in[13];
    const float* bn_g    = (const float*)d_in[14];
    const float* bn_b    = (const float*)d_in[15];
    const float* g0_w    = (const float*)d_in[16];
    const float* g0_b    = (const float*)d_in[17];
    const float* h0_w    = (const float*)d_in[18];
    const float* y1_w    = (const float*)d_in[19];
    const float* y1_b    = (const float*)d_in[20];
    const float* g1_w    = (const float*)d_in[21];
    const float* g1_b    = (const float*)d_in[22];
    const float* h1_w    = (const float*)d_in[23];
    const float* fc_w    = (const float*)d_in[24];
    const float* fc_b    = (const float*)d_in[25];

    // ---- workspace layout (no aliasing, ~46 MB) ----
    char* ws = (char*)d_ws;
    size_t off = 0;
    auto alloc = [&](size_t bytes) { void* pp = ws + off; off += (bytes + 255) & ~255ULL; return pp; };
    __hip_bfloat16* wqT  = (__hip_bfloat16*)alloc((size_t)DEPTH * 384 * 64 * 2);
    __hip_bfloat16* woT  = (__hip_bfloat16*)alloc((size_t)DEPTH * 64 * 128 * 2);
    __hip_bfloat16* w1T  = (__hip_bfloat16*)alloc((size_t)DEPTH * 512 * 64 * 2);
    __hip_bfloat16* w2T  = (__hip_bfloat16*)alloc((size_t)DEPTH * 64 * 256 * 2);
    __hip_bfloat16* h0T  = (__hip_bfloat16*)alloc((size_t)CATF * 64 * 2);
    __hip_bfloat16* y1T  = (__hip_bfloat16*)alloc((size_t)CATF * 64 * 2);
    __hip_bfloat16* Acat = (__hip_bfloat16*)alloc((size_t)B_ * KTOT * 2);
    __hip_bfloat16* WT   = (__hip_bfloat16*)alloc((size_t)CATF * KTOT * 2);
    __hip_bfloat16* G    = (__hip_bfloat16*)alloc((size_t)B_ * CATF * 2);
    float*          norm = (float*)alloc((size_t)B_ * NCONT * 4);
    float*          y1v  = (float*)alloc((size_t)B_ * NCONT * 4);

    // weight prep
    k_wT<<<576, 256, 0, stream>>>(wqkv, wqT, 64, 384);
    k_wT<<<192, 256, 0, stream>>>(wo,   woT, 128, 64);
    k_wT<<<768, 256, 0, stream>>>(wff1, w1T, 64, 512);
    k_wT<<<384, 256, 0, stream>>>(wff2, w2T, 256, 64);
    k_wT<<<512, 256, 0, stream>>>(h0_w, h0T, 64, 2048);
    k_wT<<<512, 256, 0, stream>>>(y1_w, y1T, 2048, 64);

    // transformer megakernel (emb + 6 layers + cast)
    k_former<<<NROW / 64, 128, 0, stream>>>(x_categ, embed, ln1_g, ln1_b, wqT, woT, bo,
                                            ln2_g, ln2_b, w1T, bff1, w2T, bff2, Acat);

    k_bn<<<NCONT, 256, 0, stream>>>(x_cont, bn_g, bn_b, norm, Acat);
    k_transpose<<<dim3(CATF / 64, KTOT / 64), 256, 0, stream>>>(g0_w, WT);
    k_gemm_g0<<<dim3(CATF / 128, B_ / 128), 256, 0, stream>>>(Acat, WT, g0_b, G);
    k_y1v2<<<B_ / 128, 256, 0, stream>>>(Acat, y1T, y1_b, y1v);
    k_H2<<<dim3(CATF / 128, B_ / 128), 256, 0, stream>>>(Acat, h0T, G);
    k_final<<<B_, 256, 0, stream>>>(Acat, G, norm, y1v, g1_w, g1_b, h1_w, fc_w, fc_b, (float*)d_out);
}

// Round 7
// 739.808 us; speedup vs baseline: 24.2618x; 1.2786x over previous
//
#include <hip/hip_runtime.h>
#include <hip/hip_bf16.h>

#define B_    4096
#define NC    32
#define DIM   64
#define INNER 128
#define HEADS 8
#define DH    16
#define DEPTH 6
#define NCONT 64
#define CATF  2048
#define KTOT  2112
#define NROW  (B_ * NC)          // 131072 token rows

typedef __attribute__((ext_vector_type(8))) short short8;
typedef __attribute__((ext_vector_type(4))) float f32x4;
typedef __attribute__((ext_vector_type(16))) float f32x16;
typedef __attribute__((ext_vector_type(4))) unsigned short u16x4;

__device__ __forceinline__ float bf2f(__hip_bfloat16 h) { return __bfloat162float(h); }
__device__ __forceinline__ unsigned short f2bu(float f) {
    __hip_bfloat16 h = __float2bfloat16(f);
    return *(unsigned short*)&h;
}

// ---------------------------------------------------------------------------
// Generic weight transpose+cast: W [D][K][N] fp32 -> WT [D][N][K] bf16
// ---------------------------------------------------------------------------
__global__ __launch_bounds__(256) void k_wT(const float* __restrict__ W,
                                            __hip_bfloat16* __restrict__ WT,
                                            int K, int N)
{
    size_t idx = (size_t)blockIdx.x * 256 + threadIdx.x;
    int kn = K * N;
    int d = (int)(idx / kn), rem = (int)(idx % kn);
    int n = rem / K, k = rem % K;
    WT[idx] = __float2bfloat16(W[(size_t)d * kn + (size_t)k * N + n]);
}

// ---------------------------------------------------------------------------
// Transformer megakernel: emb + 6 layers + Acat cast. 2 samples/block,
// 128 threads (2 waves, wave w = sample w). Zero __syncthreads (wave-private
// LDS). Residual in registers. QK^T via 32x32x16 MFMA + in-register softmax.
// LDS = 30.5 KB -> 5 blocks/CU. ALL LDS row strides are 16B multiples
// (48/80/272/80 B) so every short8 (b128) access is naturally aligned.
// ---------------------------------------------------------------------------
__global__ __launch_bounds__(128) void k_former(
    const int* __restrict__ x_categ, const float* __restrict__ embed,
    const float* __restrict__ ln1_g, const float* __restrict__ ln1_b,
    const __hip_bfloat16* __restrict__ wqT, const __hip_bfloat16* __restrict__ woT,
    const float* __restrict__ bo,
    const float* __restrict__ ln2_g, const float* __restrict__ ln2_b,
    const __hip_bfloat16* __restrict__ w1T, const float* __restrict__ bff1,
    const __hip_bfloat16* __restrict__ w2T, const float* __restrict__ bff2,
    __hip_bfloat16* __restrict__ Acat)
{
    __shared__ __align__(16) unsigned char Ub[64 * 136 * 2];   // 17.4 KB union
    auto U  = reinterpret_cast<__hip_bfloat16(*)[136]>(Ub);    // h / os / pg
    auto Uf = reinterpret_cast<float(*)[68]>(Ub);              // embed scratch
    __shared__ __hip_bfloat16 qh[64][24];        // per-head q [tok][dh], 48B stride
    __shared__ __hip_bfloat16 kh[64][24];        // per-head k
    __shared__ __hip_bfloat16 vth[2][16][40];    // per-head V^T [dh][tok], 80B stride
    __shared__ __hip_bfloat16 Ps[2][32][40];     // P [q][j], 80B stride (16B-aligned rows)

    const int tid = threadIdx.x;
    const int w = tid >> 6, lane = tid & 63;
    const int lo = lane & 15, g = lane >> 4;
    const int q32 = lane & 31, hi = lane >> 5;
    const int r0 = blockIdx.x * 64;
    const f32x4 z4 = f32x4{0.f, 0.f, 0.f, 0.f};

    // residual stream in registers: (token = mt*16+g*4+rg, col = nt*16+lo)
    float xacc[2][4][4];

    // embedding gather -> Uf (wave-local), then into xacc registers
    {
        int r = w * 32 + (lane >> 1), half = lane & 1;
        int grow = r0 + r;
        int tok = x_categ[grow] + 2 + 100 * (grow & 31);
        const float4* src = (const float4*)(embed + (size_t)tok * 64 + half * 32);
#pragma unroll
        for (int q4 = 0; q4 < 8; ++q4) {
            float4 v = src[q4];
            Uf[r][half * 32 + q4 * 4 + 0] = v.x; Uf[r][half * 32 + q4 * 4 + 1] = v.y;
            Uf[r][half * 32 + q4 * 4 + 2] = v.z; Uf[r][half * 32 + q4 * 4 + 3] = v.w;
        }
    }
#pragma unroll
    for (int mt = 0; mt < 2; ++mt)
#pragma unroll
        for (int nt = 0; nt < 4; ++nt)
#pragma unroll
            for (int rg = 0; rg < 4; ++rg)
                xacc[mt][nt][rg] = Uf[w * 32 + mt * 16 + g * 4 + rg][nt * 16 + lo];

    // LayerNorm: xacc regs -> U (bf16)
    auto layernorm = [&](const float* gam, const float* bet) {
        float gv[4], bv_[4];
#pragma unroll
        for (int nt = 0; nt < 4; ++nt) { gv[nt] = gam[nt * 16 + lo]; bv_[nt] = bet[nt * 16 + lo]; }
#pragma unroll
        for (int mt = 0; mt < 2; ++mt)
#pragma unroll
            for (int rg = 0; rg < 4; ++rg) {
                float s = xacc[mt][0][rg] + xacc[mt][1][rg] + xacc[mt][2][rg] + xacc[mt][3][rg];
                float q = xacc[mt][0][rg] * xacc[mt][0][rg] + xacc[mt][1][rg] * xacc[mt][1][rg]
                        + xacc[mt][2][rg] * xacc[mt][2][rg] + xacc[mt][3][rg] * xacc[mt][3][rg];
#pragma unroll
                for (int m = 1; m < 16; m <<= 1) { s += __shfl_xor(s, m); q += __shfl_xor(q, m); }
                float mu = s * (1.f / 64.f);
                float var = q * (1.f / 64.f) - mu * mu;
                float ri = rsqrtf(var + 1e-5f);
                int token = w * 32 + mt * 16 + g * 4 + rg;
#pragma unroll
                for (int nt = 0; nt < 4; ++nt)
                    U[token][nt * 16 + lo] = __float2bfloat16((xacc[mt][nt][rg] - mu) * ri * gv[nt] + bv_[nt]);
            }
    };

#pragma unroll 1
    for (int d = 0; d < DEPTH; ++d) {
        const __hip_bfloat16* wq_d = wqT + (size_t)d * 384 * 64;
        const __hip_bfloat16* wo_d = woT + (size_t)d * 64 * 128;
        const __hip_bfloat16* w1_d = w1T + (size_t)d * 512 * 64;
        const __hip_bfloat16* w2_d = w2T + (size_t)d * 64 * 256;

        // ---- LN1 ----
        layernorm(ln1_g + d * 64, ln1_b + d * 64);

        // A-frags of h (persist across heads)
        short8 af[2][2];
#pragma unroll
        for (int mt = 0; mt < 2; ++mt)
#pragma unroll
            for (int kk = 0; kk < 2; ++kk)
                af[mt][kk] = *(const short8*)&U[w * 32 + mt * 16 + lo][kk * 32 + g * 8];

        // ---- attention, per head ----
        for (int hh = 0; hh < HEADS; ++hh) {
            // qkv for this head (N=16 per part)
            f32x4 aq[2] = {z4, z4}, ak[2] = {z4, z4}, av[2] = {z4, z4};
#pragma unroll
            for (int kk = 0; kk < 2; ++kk) {
                short8 bq  = *(const short8*)&wq_d[(size_t)(hh * 16 + lo) * 64 + kk * 32 + g * 8];
                short8 bk  = *(const short8*)&wq_d[(size_t)(128 + hh * 16 + lo) * 64 + kk * 32 + g * 8];
                short8 bv2 = *(const short8*)&wq_d[(size_t)(256 + hh * 16 + lo) * 64 + kk * 32 + g * 8];
#pragma unroll
                for (int mt = 0; mt < 2; ++mt) {
                    aq[mt] = __builtin_amdgcn_mfma_f32_16x16x32_bf16(af[mt][kk], bq,  aq[mt], 0, 0, 0);
                    ak[mt] = __builtin_amdgcn_mfma_f32_16x16x32_bf16(af[mt][kk], bk,  ak[mt], 0, 0, 0);
                    av[mt] = __builtin_amdgcn_mfma_f32_16x16x32_bf16(af[mt][kk], bv2, av[mt], 0, 0, 0);
                }
            }
            // q/k scalar stores [tok][dh]; V^T packed b64 stores [dh][tok]
#pragma unroll
            for (int mt = 0; mt < 2; ++mt) {
#pragma unroll
                for (int rg = 0; rg < 4; ++rg) {
                    int tok = mt * 16 + g * 4 + rg;
                    qh[w * 32 + tok][lo] = __float2bfloat16(aq[mt][rg]);
                    kh[w * 32 + tok][lo] = __float2bfloat16(ak[mt][rg]);
                }
                u16x4 vv;
                vv.x = f2bu(av[mt][0]); vv.y = f2bu(av[mt][1]);
                vv.z = f2bu(av[mt][2]); vv.w = f2bu(av[mt][3]);
                *(u16x4*)&vth[w][lo][mt * 16 + g * 4] = vv;
            }
            // QK^T: one 32x32x16 MFMA, swapped operands -> S^T (col = q)
            // A-frag: lane reads row (lane&31), k = hi*8..hi*8+7 (16B aligned, 48B stride)
            short8 kaf = *(const short8*)&kh[w * 32 + q32][hi * 8];
            short8 qaf = *(const short8*)&qh[w * 32 + q32][hi * 8];
            f32x16 z16{};
            f32x16 St = __builtin_amdgcn_mfma_f32_32x32x16_bf16(kaf, qaf, z16, 0, 0, 0);
            // lane holds S^T[j][q]: q = lane&31, j(r) = (r&3) + 8*(r>>2) + 4*hi
            float sv[16];
            float mx = St[0] * 0.25f;
#pragma unroll
            for (int r = 0; r < 16; ++r) { sv[r] = St[r] * 0.25f; mx = fmaxf(mx, sv[r]); }
            mx = fmaxf(mx, __shfl_xor(mx, 32));
            float den = 0.f;
#pragma unroll
            for (int r = 0; r < 16; ++r) { sv[r] = __expf(sv[r] - mx); den += sv[r]; }
            den += __shfl_xor(den, 32);
            float rs = 1.f / den;
            // P store: reg group grp covers j = 8*grp + 4*hi + {0..3} -> packed b64
#pragma unroll
            for (int grp = 0; grp < 4; ++grp) {
                u16x4 pv;
                pv.x = f2bu(sv[grp * 4 + 0] * rs); pv.y = f2bu(sv[grp * 4 + 1] * rs);
                pv.z = f2bu(sv[grp * 4 + 2] * rs); pv.w = f2bu(sv[grp * 4 + 3] * rs);
                *(u16x4*)&Ps[w][q32][grp * 8 + hi * 4] = pv;
            }
            // PV -> os (U cols hh*16..)
            short8 bv = *(const short8*)&vth[w][lo][g * 8];
#pragma unroll
            for (int qt = 0; qt < 2; ++qt) {
                int qrow = qt * 16 + lo;
                short8 ap = *(const short8*)&Ps[w][qrow][g * 8];
                f32x4 ov = __builtin_amdgcn_mfma_f32_16x16x32_bf16(ap, bv, z4, 0, 0, 0);
#pragma unroll
                for (int rg = 0; rg < 4; ++rg)
                    U[w * 32 + qt * 16 + g * 4 + rg][hh * 16 + lo] = __float2bfloat16(ov[rg]);
            }
        }

        // ---- proj + residual: xacc += os @ woT^T + bo ----
        {
            short8 ap2[2][4];
#pragma unroll
            for (int mt = 0; mt < 2; ++mt)
#pragma unroll
                for (int kk = 0; kk < 4; ++kk)
                    ap2[mt][kk] = *(const short8*)&U[w * 32 + mt * 16 + lo][kk * 32 + g * 8];
            f32x4 pacc[2][4];
#pragma unroll
            for (int mt = 0; mt < 2; ++mt)
#pragma unroll
                for (int nt = 0; nt < 4; ++nt) pacc[mt][nt] = z4;
#pragma unroll
            for (int kk = 0; kk < 4; ++kk)
#pragma unroll
                for (int nt = 0; nt < 4; ++nt) {
                    short8 b = *(const short8*)&wo_d[(size_t)(nt * 16 + lo) * 128 + kk * 32 + g * 8];
#pragma unroll
                    for (int mt = 0; mt < 2; ++mt)
                        pacc[mt][nt] = __builtin_amdgcn_mfma_f32_16x16x32_bf16(ap2[mt][kk], b, pacc[mt][nt], 0, 0, 0);
                }
            float bov[4];
#pragma unroll
            for (int nt = 0; nt < 4; ++nt) bov[nt] = bo[d * 64 + nt * 16 + lo];
#pragma unroll
            for (int mt = 0; mt < 2; ++mt)
#pragma unroll
                for (int nt = 0; nt < 4; ++nt)
#pragma unroll
                    for (int rg = 0; rg < 4; ++rg)
                        xacc[mt][nt][rg] += pacc[mt][nt][rg] + bov[nt];
        }

        // ---- LN2 ----
        layernorm(ln2_g + d * 64, ln2_b + d * 64);

        // ---- ff1(geglu) + ff2, chunked (64 p-cols at a time) ----
        {
            short8 af2[2][2];
#pragma unroll
            for (int mt = 0; mt < 2; ++mt)
#pragma unroll
                for (int kk = 0; kk < 2; ++kk)
                    af2[mt][kk] = *(const short8*)&U[w * 32 + mt * 16 + lo][kk * 32 + g * 8];
            f32x4 acc2[2][4];
#pragma unroll
            for (int mt = 0; mt < 2; ++mt)
#pragma unroll
                for (int nt = 0; nt < 4; ++nt) acc2[mt][nt] = z4;

            for (int c4 = 0; c4 < 4; ++c4) {
                // geglu in two nt-halves (keeps aa/agg at [2][2] for VGPR)
#pragma unroll
                for (int nh = 0; nh < 2; ++nh) {
                    f32x4 aa[2][2], agg[2][2];
#pragma unroll
                    for (int mt = 0; mt < 2; ++mt)
#pragma unroll
                        for (int nj = 0; nj < 2; ++nj) { aa[mt][nj] = z4; agg[mt][nj] = z4; }
#pragma unroll
                    for (int kk = 0; kk < 2; ++kk)
#pragma unroll
                        for (int nj = 0; nj < 2; ++nj) {
                            int nt = nh * 2 + nj;
                            short8 ba = *(const short8*)&w1_d[(size_t)(c4 * 64 + nt * 16 + lo) * 64 + kk * 32 + g * 8];
                            short8 bg = *(const short8*)&w1_d[(size_t)(256 + c4 * 64 + nt * 16 + lo) * 64 + kk * 32 + g * 8];
#pragma unroll
                            for (int mt = 0; mt < 2; ++mt) {
                                aa[mt][nj]  = __builtin_amdgcn_mfma_f32_16x16x32_bf16(af2[mt][kk], ba, aa[mt][nj], 0, 0, 0);
                                agg[mt][nj] = __builtin_amdgcn_mfma_f32_16x16x32_bf16(af2[mt][kk], bg, agg[mt][nj], 0, 0, 0);
                            }
                        }
#pragma unroll
                    for (int mt = 0; mt < 2; ++mt)
#pragma unroll
                        for (int nj = 0; nj < 2; ++nj)
#pragma unroll
                            for (int rg = 0; rg < 4; ++rg) {
                                int nt = nh * 2 + nj;
                                int col = c4 * 64 + nt * 16 + lo;
                                float a  = aa[mt][nj][rg]  + bff1[d * 512 + col];
                                float gg = agg[mt][nj][rg] + bff1[d * 512 + 256 + col];
                                float gl = 0.5f * gg * (1.f + erff(gg * 0.70710678118654752f));
                                U[w * 32 + mt * 16 + g * 4 + rg][nt * 16 + lo] = __float2bfloat16(a * gl);
                            }
                }
                // ff2 partial: acc2 += pg @ w2T^T (K-chunk c4)
                short8 apg[2][2];
#pragma unroll
                for (int mt = 0; mt < 2; ++mt)
#pragma unroll
                    for (int kk = 0; kk < 2; ++kk)
                        apg[mt][kk] = *(const short8*)&U[w * 32 + mt * 16 + lo][kk * 32 + g * 8];
#pragma unroll
                for (int kk = 0; kk < 2; ++kk)
#pragma unroll
                    for (int nt = 0; nt < 4; ++nt) {
                        short8 bb = *(const short8*)&w2_d[(size_t)(nt * 16 + lo) * 256 + c4 * 64 + kk * 32 + g * 8];
#pragma unroll
                        for (int mt = 0; mt < 2; ++mt)
                            acc2[mt][nt] = __builtin_amdgcn_mfma_f32_16x16x32_bf16(apg[mt][kk], bb, acc2[mt][nt], 0, 0, 0);
                    }
            }
            // residual
            float b2v[4];
#pragma unroll
            for (int nt = 0; nt < 4; ++nt) b2v[nt] = bff2[d * 64 + nt * 16 + lo];
#pragma unroll
            for (int mt = 0; mt < 2; ++mt)
#pragma unroll
                for (int nt = 0; nt < 4; ++nt)
#pragma unroll
                    for (int rg = 0; rg < 4; ++rg)
                        xacc[mt][nt][rg] += acc2[mt][nt][rg] + b2v[nt];
        }
    }

    // write Acat (bf16, cols 0..2047) straight from registers
    {
        size_t base = (size_t)(blockIdx.x * 2 + w) * KTOT;
#pragma unroll
        for (int mt = 0; mt < 2; ++mt)
#pragma unroll
            for (int rg = 0; rg < 4; ++rg) {
                int token = mt * 16 + g * 4 + rg;
#pragma unroll
                for (int nt = 0; nt < 4; ++nt)
                    Acat[base + token * 64 + nt * 16 + lo] = __float2bfloat16(xacc[mt][nt][rg]);
            }
    }
}

// ---------------------------------------------------------------------------
// BatchNorm1d (batch stats), one block per feature column.
// ---------------------------------------------------------------------------
__global__ __launch_bounds__(256) void k_bn(
    const float* __restrict__ x_cont, const float* __restrict__ bn_g, const float* __restrict__ bn_b,
    float* __restrict__ normed, __hip_bfloat16* __restrict__ Acat)
{
    const int c = blockIdx.x;
    const int tid = threadIdx.x;
    float sum = 0.f, sq = 0.f;
    for (int rr = tid; rr < B_; rr += 256) { float v = x_cont[rr * NCONT + c]; sum += v; sq += v * v; }
    __shared__ float ssum[256], ssq[256];
    ssum[tid] = sum; ssq[tid] = sq;
    __syncthreads();
    for (int st = 128; st > 0; st >>= 1) {
        if (tid < st) { ssum[tid] += ssum[tid + st]; ssq[tid] += ssq[tid + st]; }
        __syncthreads();
    }
    float mu  = ssum[0] * (1.f / B_);
    float var = ssq[0] * (1.f / B_) - mu * mu;
    float ri  = rsqrtf(var + 1e-5f);
    float gg = bn_g[c], bb = bn_b[c];
    for (int rr = tid; rr < B_; rr += 256) {
        float v = (x_cont[rr * NCONT + c] - mu) * ri * gg + bb;
        normed[rr * NCONT + c] = v;
        Acat[(size_t)rr * KTOT + CATF + c] = __float2bfloat16(v);
    }
}

// ---------------------------------------------------------------------------
// g0_w [2112,2048] fp32 -> WT [2048,2112] bf16 (k-contiguous)
// ---------------------------------------------------------------------------
__global__ __launch_bounds__(256) void k_transpose(
    const float* __restrict__ W, __hip_bfloat16* __restrict__ WT)
{
    __shared__ float tile[64][65];
    const int n0 = blockIdx.x * 64, k0 = blockIdx.y * 64;
    const int tid = threadIdx.x;
    for (int e = tid; e < 64 * 16; e += 256) {
        int rr = e >> 4, c4 = e & 15;
        float4 v = *(const float4*)&W[(size_t)(k0 + rr) * CATF + n0 + c4 * 4];
        tile[rr][c4 * 4 + 0] = v.x; tile[rr][c4 * 4 + 1] = v.y;
        tile[rr][c4 * 4 + 2] = v.z; tile[rr][c4 * 4 + 3] = v.w;
    }
    __syncthreads();
    for (int e = tid; e < 64 * 32; e += 256) {
        int n = e >> 5, kp = e & 31;
        __hip_bfloat16 h0 = __float2bfloat16(tile[kp * 2 + 0][n]);
        __hip_bfloat16 h1 = __float2bfloat16(tile[kp * 2 + 1][n]);
        unsigned u = ((unsigned)(*(unsigned short*)&h1) << 16) | (unsigned)(*(unsigned short*)&h0);
        *(unsigned*)&WT[(size_t)(n0 + n) * KTOT + k0 + kp * 2] = u;
    }
}

// ---------------------------------------------------------------------------
// G = relu(Acat[4096,2112] @ g0_w + g0_b), bf16 MFMA, 128x128 tiles, BK=64
// ---------------------------------------------------------------------------
__global__ __launch_bounds__(256) void k_gemm_g0(
    const __hip_bfloat16* __restrict__ Acat, const __hip_bfloat16* __restrict__ WT,
    const float* __restrict__ g0_b, __hip_bfloat16* __restrict__ G)
{
    __shared__ __hip_bfloat16 At[128][72];
    __shared__ __hip_bfloat16 Bt[128][72];
    const int tid = threadIdx.x;
    const int m0 = blockIdx.y * 128, n0 = blockIdx.x * 128;
    const int w = tid >> 6, lane = tid & 63, g = lane >> 4;
    const int wr = w >> 1, wc = w & 1;

    f32x4 acc[4][4];
#pragma unroll
    for (int mi = 0; mi < 4; ++mi)
#pragma unroll
        for (int ni = 0; ni < 4; ++ni) acc[mi][ni] = f32x4{0.f, 0.f, 0.f, 0.f};

    const int row_a = wr * 64 + (lane & 15);
    const int row_b = wc * 64 + (lane & 15);

    for (int kt = 0; kt < KTOT / 64; ++kt) {
        const int k0 = kt * 64;
#pragma unroll
        for (int t = 0; t < 4; ++t) {
            int e = tid + t * 256; int rr = e >> 3, seg = e & 7;
            *(uint4*)&At[rr][seg * 8] = *(const uint4*)&Acat[(size_t)(m0 + rr) * KTOT + k0 + seg * 8];
        }
#pragma unroll
        for (int t = 0; t < 4; ++t) {
            int e = tid + t * 256; int rr = e >> 3, seg = e & 7;
            *(uint4*)&Bt[rr][seg * 8] = *(const uint4*)&WT[(size_t)(n0 + rr) * KTOT + k0 + seg * 8];
        }
        __syncthreads();
        short8 af[4][2], bfr[4][2];
#pragma unroll
        for (int mi = 0; mi < 4; ++mi)
#pragma unroll
            for (int kk = 0; kk < 2; ++kk)
                af[mi][kk] = *(const short8*)&At[row_a + mi * 16][kk * 32 + g * 8];
#pragma unroll
        for (int ni = 0; ni < 4; ++ni)
#pragma unroll
            for (int kk = 0; kk < 2; ++kk)
                bfr[ni][kk] = *(const short8*)&Bt[row_b + ni * 16][kk * 32 + g * 8];
#pragma unroll
        for (int kk = 0; kk < 2; ++kk)
#pragma unroll
            for (int mi = 0; mi < 4; ++mi)
#pragma unroll
                for (int ni = 0; ni < 4; ++ni)
                    acc[mi][ni] = __builtin_amdgcn_mfma_f32_16x16x32_bf16(af[mi][kk], bfr[ni][kk], acc[mi][ni], 0, 0, 0);
        __syncthreads();
    }

#pragma unroll
    for (int mi = 0; mi < 4; ++mi)
#pragma unroll
        for (int ni = 0; ni < 4; ++ni)
#pragma unroll
            for (int reg = 0; reg < 4; ++reg) {
                int row = m0 + wr * 64 + mi * 16 + (lane >> 4) * 4 + reg;
                int col = n0 + wc * 64 + ni * 16 + (lane & 15);
                float v = acc[mi][ni][reg] + g0_b[col];
                G[(size_t)row * CATF + col] = __float2bfloat16(fmaxf(v, 0.f));
            }
}

// ---------------------------------------------------------------------------
// y1 = flat_categ @ y1_w + y1_b.  MFMA, M=4096 N=64 K=2048, 128-row blocks.
// ---------------------------------------------------------------------------
__global__ __launch_bounds__(256) void k_y1v2(
    const __hip_bfloat16* __restrict__ Acat, const __hip_bfloat16* __restrict__ y1T,
    const float* __restrict__ y1_b, float* __restrict__ y1)
{
    __shared__ __hip_bfloat16 At[128][136];
    __shared__ __hip_bfloat16 Bt[64][136];
    const int tid = threadIdx.x;
    const size_t m0 = (size_t)blockIdx.x * 128;
    const int w = tid >> 6, lane = tid & 63, lo = lane & 15, g = lane >> 4;
    f32x4 acc[2][4];
#pragma unroll
    for (int mt = 0; mt < 2; ++mt)
#pragma unroll
        for (int nt = 0; nt < 4; ++nt) acc[mt][nt] = f32x4{0.f, 0.f, 0.f, 0.f};
    for (int kt = 0; kt < 16; ++kt) {
        if (kt) __syncthreads();
#pragma unroll
        for (int t = 0; t < 8; ++t) {
            int e = tid + t * 256; int row = e >> 4, seg = e & 15;
            *(uint4*)&At[row][seg * 8] = *(const uint4*)&Acat[(m0 + row) * KTOT + kt * 128 + seg * 8];
        }
#pragma unroll
        for (int t = 0; t < 4; ++t) {
            int e = tid + t * 256; int row = e >> 4, seg = e & 15;
            *(uint4*)&Bt[row][seg * 8] = *(const uint4*)&y1T[(size_t)row * 2048 + kt * 128 + seg * 8];
        }
        __syncthreads();
#pragma unroll
        for (int kk = 0; kk < 4; ++kk) {
            short8 a[2], b[4];
#pragma unroll
            for (int mt = 0; mt < 2; ++mt) a[mt] = *(const short8*)&At[w * 32 + mt * 16 + lo][kk * 32 + g * 8];
#pragma unroll
            for (int nt = 0; nt < 4; ++nt) b[nt] = *(const short8*)&Bt[nt * 16 + lo][kk * 32 + g * 8];
#pragma unroll
            for (int mt = 0; mt < 2; ++mt)
#pragma unroll
                for (int nt = 0; nt < 4; ++nt)
                    acc[mt][nt] = __builtin_amdgcn_mfma_f32_16x16x32_bf16(a[mt], b[nt], acc[mt][nt], 0, 0, 0);
        }
    }
#pragma unroll
    for (int mt = 0; mt < 2; ++mt)
#pragma unroll
        for (int nt = 0; nt < 4; ++nt)
#pragma unroll
            for (int rg = 0; rg < 4; ++rg) {
                size_t row = m0 + w * 32 + mt * 16 + g * 4 + rg;
                int col = nt * 16 + lo;
                y1[row * 64 + col] = acc[mt][nt][rg] + y1_b[col];
            }
}

// ---------------------------------------------------------------------------
// H = G * (normed @ h0_w), in-place over G. MFMA, M=4096 N=2048 K=64.
// ---------------------------------------------------------------------------
__global__ __launch_bounds__(256) void k_H2(
    const __hip_bfloat16* __restrict__ Acat, const __hip_bfloat16* __restrict__ h0T,
    __hip_bfloat16* __restrict__ G)
{
    __shared__ __hip_bfloat16 At[128][72];
    const int tid = threadIdx.x;
    const int m0 = blockIdx.y * 128, n0 = blockIdx.x * 128;
    const int w = tid >> 6, lane = tid & 63, lo = lane & 15, g = lane >> 4;
    const int wr = w >> 1, wc = w & 1;
#pragma unroll
    for (int t = 0; t < 4; ++t) {
        int e = tid + t * 256; int row = e >> 3, seg = e & 7;
        *(uint4*)&At[row][seg * 8] = *(const uint4*)&Acat[(size_t)(m0 + row) * KTOT + CATF + seg * 8];
    }
    __syncthreads();
    f32x4 acc[4][4];
#pragma unroll
    for (int mt = 0; mt < 4; ++mt)
#pragma unroll
        for (int nt = 0; nt < 4; ++nt) acc[mt][nt] = f32x4{0.f, 0.f, 0.f, 0.f};
#pragma unroll
    for (int kk = 0; kk < 2; ++kk) {
        short8 a[4], b[4];
#pragma unroll
        for (int mt = 0; mt < 4; ++mt) a[mt] = *(const short8*)&At[wr * 64 + mt * 16 + lo][kk * 32 + g * 8];
#pragma unroll
        for (int nt = 0; nt < 4; ++nt)
            b[nt] = *(const short8*)&h0T[(size_t)(n0 + wc * 64 + nt * 16 + lo) * 64 + kk * 32 + g * 8];
#pragma unroll
        for (int mt = 0; mt < 4; ++mt)
#pragma unroll
            for (int nt = 0; nt < 4; ++nt)
                acc[mt][nt] = __builtin_amdgcn_mfma_f32_16x16x32_bf16(a[mt], b[nt], acc[mt][nt], 0, 0, 0);
    }
#pragma unroll
    for (int mt = 0; mt < 4; ++mt)
#pragma unroll
        for (int nt = 0; nt < 4; ++nt)
#pragma unroll
            for (int rg = 0; rg < 4; ++rg) {
                size_t row = (size_t)m0 + wr * 64 + mt * 16 + g * 4 + rg;
                int col = n0 + wc * 64 + nt * 16 + lo;
                size_t offo = row * CATF + col;
                G[offo] = __float2bfloat16(bf2f(G[offo]) * acc[mt][nt][rg]);
            }
}

// ---------------------------------------------------------------------------
// Final: norms, alpha, c0/c1 combine, fc dot, sigmoid. One block per row.
// ---------------------------------------------------------------------------
__global__ __launch_bounds__(256) void k_final(
    const __hip_bfloat16* __restrict__ Acat, const __hip_bfloat16* __restrict__ H,
    const float* __restrict__ normed, const float* __restrict__ y1,
    const float* __restrict__ g1_w, const float* __restrict__ g1_b, const float* __restrict__ h1_w,
    const float* __restrict__ fc_w, const float* __restrict__ fc_b,
    float* __restrict__ out)
{
    const int b = blockIdx.x;
    const int tid = threadIdx.x;
    const __hip_bfloat16* xrow = Acat + (size_t)b * KTOT;
    const __hip_bfloat16* hrow = H + (size_t)b * CATF;

    __shared__ float r1[256], r2[256];
    float sx = 0.f, sh = 0.f;
    for (int n = tid; n < CATF; n += 256) {
        float xv = bf2f(xrow[n]); sx += xv * xv;
        float hv = bf2f(hrow[n]); sh += hv * hv;
    }
    r1[tid] = sx; r2[tid] = sh;
    __syncthreads();
    for (int st = 128; st > 0; st >>= 1) {
        if (tid < st) { r1[tid] += r1[tid + st]; r2[tid] += r2[tid + st]; }
        __syncthreads();
    }
    float alpha0 = fminf(fmaxf(sqrtf(r1[0]) / (sqrtf(r2[0]) + 1e-12f) * 0.2f, 0.f), 1.f);
    __syncthreads();

    float pd = 0.f;
    for (int n = tid; n < CATF; n += 256) {
        float c0 = bf2f(xrow[n]) + alpha0 * bf2f(hrow[n]);
        pd += c0 * fc_w[n];
    }
    r1[tid] = pd;
    __syncthreads();
    for (int st = 128; st > 0; st >>= 1) {
        if (tid < st) r1[tid] += r1[tid + st];
        __syncthreads();
    }
    float dot0 = r1[0];

    __shared__ float ny[128];
    __shared__ float c1dot;
    if (tid < 64) ny[tid] = normed[b * NCONT + tid];
    else if (tid < 128) ny[tid] = y1[b * NCONT + tid - 64];
    __syncthreads();

    if (tid < 64) {
        const int j = tid;
        float g = g1_b[j];
        for (int k = 0; k < 128; ++k) g += ny[k] * g1_w[k * 64 + j];
        g = fmaxf(g, 0.f);
        float hv = 0.f;
        for (int k = 0; k < 64; ++k) hv += ny[64 + k] * h1_w[k * 64 + j];
        float H1 = g * hv;
        float nj = ny[j];
        float snx = nj * nj, snh = H1 * H1;
        for (int m = 1; m < 64; m <<= 1) { snx += __shfl_xor(snx, m, 64); snh += __shfl_xor(snh, m, 64); }
        float a1 = fminf(fmaxf(sqrtf(snx) / (sqrtf(snh) + 1e-12f) * 0.2f, 0.f), 1.f);
        float d1 = (nj + a1 * H1) * fc_w[CATF + j];
        for (int m = 1; m < 64; m <<= 1) d1 += __shfl_xor(d1, m, 64);
        if (tid == 0) c1dot = d1;
    }
    __syncthreads();
    if (tid == 0) {
        float logit = dot0 + c1dot + fc_b[0];
        out[b] = 1.f / (1.f + expf(-logit));
    }
}

// ---------------------------------------------------------------------------
extern "C" void kernel_launch(void* const* d_in, const int* in_sizes, int n_in,
                              void* d_out, int out_size, void* d_ws, size_t ws_size,
                              hipStream_t stream)
{
    const int*   x_categ = (const int*)d_in[0];
    const float* x_cont  = (const float*)d_in[1];
    const float* embed   = (const float*)d_in[2];
    const float* ln1_g   = (const float*)d_in[3];
    const float* ln1_b   = (const float*)d_in[4];
    const float* wqkv    = (const float*)d_in[5];
    const float* wo      = (const float*)d_in[6];
    const float* bo      = (const float*)d_in[7];
    const float* ln2_g   = (const float*)d_in[8];
    const float* ln2_b   = (const float*)d_in[9];
    const float* wff1    = (const float*)d_in[10];
    const float* bff1    = (const float*)d_in[11];
    const float* wff2    = (const float*)d_in[12];
    const float* bff2    = (const float*)d_in[13];
    const float* bn_g    = (const float*)d_in[14];
    const float* bn_b    = (const float*)d_in[15];
    const float* g0_w    = (const float*)d_in[16];
    const float* g0_b    = (const float*)d_in[17];
    const float* h0_w    = (const float*)d_in[18];
    const float* y1_w    = (const float*)d_in[19];
    const float* y1_b    = (const float*)d_in[20];
    const float* g1_w    = (const float*)d_in[21];
    const float* g1_b    = (const float*)d_in[22];
    const float* h1_w    = (const float*)d_in[23];
    const float* fc_w    = (const float*)d_in[24];
    const float* fc_b    = (const float*)d_in[25];

    // ---- workspace layout (no aliasing, ~46 MB) ----
    char* ws = (char*)d_ws;
    size_t off = 0;
    auto alloc = [&](size_t bytes) { void* pp = ws + off; off += (bytes + 255) & ~255ULL; return pp; };
    __hip_bfloat16* wqT  = (__hip_bfloat16*)alloc((size_t)DEPTH * 384 * 64 * 2);
    __hip_bfloat16* woT  = (__hip_bfloat16*)alloc((size_t)DEPTH * 64 * 128 * 2);
    __hip_bfloat16* w1T  = (__hip_bfloat16*)alloc((size_t)DEPTH * 512 * 64 * 2);
    __hip_bfloat16* w2T  = (__hip_bfloat16*)alloc((size_t)DEPTH * 64 * 256 * 2);
    __hip_bfloat16* h0T  = (__hip_bfloat16*)alloc((size_t)CATF * 64 * 2);
    __hip_bfloat16* y1T  = (__hip_bfloat16*)alloc((size_t)CATF * 64 * 2);
    __hip_bfloat16* Acat = (__hip_bfloat16*)alloc((size_t)B_ * KTOT * 2);
    __hip_bfloat16* WT   = (__hip_bfloat16*)alloc((size_t)CATF * KTOT * 2);
    __hip_bfloat16* G    = (__hip_bfloat16*)alloc((size_t)B_ * CATF * 2);
    float*          norm = (float*)alloc((size_t)B_ * NCONT * 4);
    float*          y1v  = (float*)alloc((size_t)B_ * NCONT * 4);

    // weight prep
    k_wT<<<576, 256, 0, stream>>>(wqkv, wqT, 64, 384);
    k_wT<<<192, 256, 0, stream>>>(wo,   woT, 128, 64);
    k_wT<<<768, 256, 0, stream>>>(wff1, w1T, 64, 512);
    k_wT<<<384, 256, 0, stream>>>(wff2, w2T, 256, 64);
    k_wT<<<512, 256, 0, stream>>>(h0_w, h0T, 64, 2048);
    k_wT<<<512, 256, 0, stream>>>(y1_w, y1T, 2048, 64);

    // transformer megakernel (emb + 6 layers + cast)
    k_former<<<NROW / 64, 128, 0, stream>>>(x_categ, embed, ln1_g, ln1_b, wqT, woT, bo,
                                            ln2_g, ln2_b, w1T, bff1, w2T, bff2, Acat);

    k_bn<<<NCONT, 256, 0, stream>>>(x_cont, bn_g, bn_b, norm, Acat);
    k_transpose<<<dim3(CATF / 64, KTOT / 64), 256, 0, stream>>>(g0_w, WT);
    k_gemm_g0<<<dim3(CATF / 128, B_ / 128), 256, 0, stream>>>(Acat, WT, g0_b, G);
    k_y1v2<<<B_ / 128, 256, 0, stream>>>(Acat, y1T, y1_b, y1v);
    k_H2<<<dim3(CATF / 128, B_ / 128), 256, 0, stream>>>(Acat, h0T, G);
    k_final<<<B_, 256, 0, stream>>>(Acat, G, norm, y1v, g1_w, g1_b, h1_w, fc_w, fc_b, (float*)d_out);
}